// Round 3
// baseline (1350.232 us; speedup 1.0000x reference)
//
#include <hip/hip_runtime.h>
#include <hip/hip_bf16.h>

#define T_TOK  2048
#define DIMSZ  2048
#define NEXP   32
#define INTERS 1024
#define SINTER 2048
#define NTOPK  6

typedef __bf16 bf16x8 __attribute__((ext_vector_type(8)));
typedef float  f32x4  __attribute__((ext_vector_type(4)));

__device__ __forceinline__ unsigned short f2b(float f) {
    __hip_bfloat16 h = __float2bfloat16(f);
    return __builtin_bit_cast(unsigned short, h);
}

// async global->LDS, 16B per lane. LDS dest is wave-uniform base + lane*16.
__device__ __forceinline__ void gl_lds16(const unsigned short* g, unsigned short* l) {
    __builtin_amdgcn_global_load_lds(
        (const __attribute__((address_space(1))) void*)g,
        (__attribute__((address_space(3))) void*)l, 16, 0, 0);
}

// ---------------- f32 -> bf16: single kernel, 7 tensors ----------------
struct CvtJobs {
    const float4* src[7];
    ushort4*      dst[7];
    int           n4[7];
};
__global__ __launch_bounds__(256) void cvt_multi(CvtJobs jobs) {
    const int gtid = blockIdx.x * blockDim.x + threadIdx.x;
    const int gstride = gridDim.x * blockDim.x;
    #pragma unroll
    for (int j = 0; j < 7; ++j) {
        const float4* __restrict__ s = jobs.src[j];
        ushort4* __restrict__ d = jobs.dst[j];
        const int n4 = jobs.n4[j];
        for (int i = gtid; i < n4; i += gstride) {
            float4 v = s[i];
            ushort4 o;
            o.x = f2b(v.x); o.y = f2b(v.y); o.z = f2b(v.z); o.w = f2b(v.w);
            d[i] = o;
        }
    }
}

// single-tensor cvt (fallback path: x only)
__global__ void cvt_f2b(const float4* __restrict__ src, ushort4* __restrict__ dst, int n4) {
    int stride = gridDim.x * blockDim.x;
    for (int i = blockIdx.x * blockDim.x + threadIdx.x; i < n4; i += stride) {
        float4 v = src[i];
        ushort4 o;
        o.x = f2b(v.x); o.y = f2b(v.y); o.z = f2b(v.z); o.w = f2b(v.w);
        dst[i] = o;
    }
}

// ---------------- gate scores: scores[T,E] = sigmoid(x @ gw^T), fp32 ----------------
#define SCT 8
#define SCK 128
__global__ __launch_bounds__(256) void gate_scores_kernel(
    const float* __restrict__ x, const float* __restrict__ gw, float* __restrict__ scores)
{
    __shared__ float xs[SCT * SCK];            // 8 x 128
    __shared__ float gs[NEXP * (SCK + 1)];     // 32 x 129 (pad: conflict-free)
    const int t0 = blockIdx.x * SCT;
    const int tid = threadIdx.x;
    const int tl = tid >> 5, e = tid & 31;
    float acc = 0.f;
    for (int k0 = 0; k0 < DIMSZ; k0 += SCK) {
        {
            int row = tid >> 5, d4 = tid & 31;
            *(float4*)&xs[row * SCK + d4 * 4] =
                *(const float4*)&x[(size_t)(t0 + row) * DIMSZ + k0 + d4 * 4];
        }
        #pragma unroll
        for (int i = 0; i < 4; ++i) {
            int lin = tid + i * 256;
            int row = lin >> 5, d4 = lin & 31;
            float4 v = *(const float4*)&gw[(size_t)row * DIMSZ + k0 + d4 * 4];
            float* dst = &gs[row * (SCK + 1) + d4 * 4];
            dst[0] = v.x; dst[1] = v.y; dst[2] = v.z; dst[3] = v.w;
        }
        __syncthreads();
        #pragma unroll 8
        for (int d = 0; d < SCK; ++d)
            acc += xs[tl * SCK + d] * gs[e * (SCK + 1) + d];
        __syncthreads();
    }
    scores[(size_t)(t0 + tl) * NEXP + e] = 1.f / (1.f + expf(-acc));
}

// ---------------- top-k routing (one thread per token) ----------------
__global__ __launch_bounds__(256) void topk_kernel(
    const float* __restrict__ scores,
    int* __restrict__ counts, int* __restrict__ toklist, float* __restrict__ wgts)
{
    int t = blockIdx.x * 256 + threadIdx.x;
    if (t >= T_TOK) return;
    float sc[NEXP];
    #pragma unroll
    for (int e = 0; e < NEXP; ++e) sc[e] = scores[(size_t)t * NEXP + e];

    float gsc[8];
    #pragma unroll
    for (int g = 0; g < 8; ++g) {
        float m = sc[4 * g];
        #pragma unroll
        for (int j = 1; j < 4; ++j) m = fmaxf(m, sc[4 * g + j]);
        gsc[g] = m;
    }
    bool gsel[8] = {false, false, false, false, false, false, false, false};
    for (int it = 0; it < 4; ++it) {
        int bi = -1; float bv = -1e30f;
        #pragma unroll
        for (int g = 0; g < 8; ++g)
            if (!gsel[g] && gsc[g] > bv) { bv = gsc[g]; bi = g; }
        gsel[bi] = true;
    }
    bool esel[NEXP];
    #pragma unroll
    for (int e = 0; e < NEXP; ++e) esel[e] = false;
    int   idx[NTOPK];
    float w[NTOPK];
    float sum = 0.f;
    for (int it = 0; it < NTOPK; ++it) {
        int bi = -1; float bv = -1e30f;
        #pragma unroll
        for (int e = 0; e < NEXP; ++e) {
            if (!gsel[e >> 2] || esel[e]) continue;
            if (sc[e] > bv) { bv = sc[e]; bi = e; }
        }
        esel[bi] = true; idx[it] = bi; w[it] = bv; sum += bv;
    }
    float scale = 2.5f / sum;
    for (int k = 0; k < NTOPK; ++k) {
        int e = idx[k];
        int s = atomicAdd(&counts[e], 1);
        toklist[e * T_TOK + s] = (t << 3) | k;
        wgts[e * T_TOK + s]   = w[k] * scale;
    }
}

// =======================================================================
// MERGED fc1: grid (16, 16, NEXP+1). z<NEXP: routed expert (x<8 active);
// z==NEXP: shared expert (all 16 x). H = silu(A@B1^T) * (A@B2^T), bf16.
// Staging: global_load_lds w/ both-sides XOR swizzle (proven rounds 1-2).
// =======================================================================
__global__ __launch_bounds__(256, 2) void fc1_merged(
    const unsigned short* __restrict__ A,
    const unsigned short* __restrict__ w11b, const unsigned short* __restrict__ w33b,
    const unsigned short* __restrict__ sw1b, const unsigned short* __restrict__ sw3b,
    unsigned short* __restrict__ h, unsigned short* __restrict__ hs,
    const int* __restrict__ counts, const int* __restrict__ toklist)
{
    constexpr int BM = 128, BN = 128, BK = 64, LDK = 64, K = DIMSZ;
    __shared__ unsigned short As[BM * LDK];
    __shared__ unsigned short B1s[BN * LDK];
    __shared__ unsigned short B2s[BN * LDK];
    __shared__ int aRowS[BM];
    __shared__ int cRowS[BM];

    const int tid = threadIdx.x;
    const int e   = blockIdx.z;
    const bool SH = (e == NEXP);
    const int N   = SH ? SINTER : INTERS;
    const int n0  = blockIdx.x * BN;
    if (n0 >= N) return;                      // routed z: x in 8..15 inactive
    const int m0  = blockIdx.y * BM;
    const int M   = SH ? T_TOK : counts[e];
    if (m0 >= M) return;

    const size_t eoff = SH ? 0 : (size_t)e * INTERS * DIMSZ;
    const unsigned short* B1 = (SH ? sw1b : w11b) + eoff;
    const unsigned short* B2 = (SH ? sw3b : w33b) + eoff;
    unsigned short* Hout = SH ? hs : h;

    if (tid < BM) {
        int r = m0 + tid;
        if (SH) { aRowS[tid] = r; cRowS[tid] = r; }
        else if (r < M) {
            int ent = toklist[e * T_TOK + r];
            int t = ent >> 3, k = ent & 7;
            aRowS[tid] = t; cRowS[tid] = t * NTOPK + k;
        } else { aRowS[tid] = 0; cRowS[tid] = -1; }
    }
    __syncthreads();

    f32x4 acc1[4][4] = {};
    f32x4 acc2[4][4] = {};

    const int wave = tid >> 6;
    const int lane = tid & 63;
    const int wm = (wave >> 1) * 64;
    const int wn = (wave & 1) * 64;
    const int lm = lane & 15;
    const int quad = lane >> 4;

    // per-lane pre-swizzled source pointers (4 chunks of 8 rows each)
    const unsigned short *aP[4], *b1P[4], *b2P[4];
    {
        const int l8 = lane >> 3;             // row within chunk (0..7)
        const int sg = (lane & 7) ^ l8;       // pre-swizzled 16B slot within row
        #pragma unroll
        for (int i = 0; i < 4; ++i) {
            const int c = wave * 4 + i;       // chunk 0..15, rows 8c..8c+7
            const int r = c * 8 + l8;
            aP[i]  = A  + (size_t)aRowS[r] * K + sg * 8;
            b1P[i] = B1 + (size_t)(n0 + r) * K + sg * 8;
            b2P[i] = B2 + (size_t)(n0 + r) * K + sg * 8;
        }
    }

    for (int k0 = 0; k0 < K; k0 += BK) {
        #pragma unroll
        for (int i = 0; i < 4; ++i) {
            const int c = wave * 4 + i;
            gl_lds16(aP[i]  + k0, &As [c * 512]);
            gl_lds16(b1P[i] + k0, &B1s[c * 512]);
            gl_lds16(b2P[i] + k0, &B2s[c * 512]);
        }
        __syncthreads();   // drains vmcnt(0) -> gl_lds data visible
        #pragma unroll
        for (int kh = 0; kh < 2; ++kh) {
            const int soff = (((kh << 2) | quad) ^ (lm & 7)) << 3;
            bf16x8 af[4], bf1[4], bf2[4];
            #pragma unroll
            for (int ti = 0; ti < 4; ++ti)
                af[ti] = *(const bf16x8*)&As[(wm + ti * 16 + lm) * LDK + soff];
            #pragma unroll
            for (int tj = 0; tj < 4; ++tj) {
                bf1[tj] = *(const bf16x8*)&B1s[(wn + tj * 16 + lm) * LDK + soff];
                bf2[tj] = *(const bf16x8*)&B2s[(wn + tj * 16 + lm) * LDK + soff];
            }
            #pragma unroll
            for (int ti = 0; ti < 4; ++ti)
                #pragma unroll
                for (int tj = 0; tj < 4; ++tj) {
                    acc1[ti][tj] = __builtin_amdgcn_mfma_f32_16x16x32_bf16(
                        af[ti], bf1[tj], acc1[ti][tj], 0, 0, 0);
                    acc2[ti][tj] = __builtin_amdgcn_mfma_f32_16x16x32_bf16(
                        af[ti], bf2[tj], acc2[ti][tj], 0, 0, 0);
                }
        }
        __syncthreads();
    }

    #pragma unroll
    for (int ti = 0; ti < 4; ++ti) {
        #pragma unroll
        for (int r = 0; r < 4; ++r) {
            int lrow = wm + ti * 16 + quad * 4 + r;
            int cr = cRowS[lrow];
            if (cr < 0) continue;
            #pragma unroll
            for (int tj = 0; tj < 4; ++tj) {
                int nn = n0 + wn + tj * 16 + lm;
                float g = acc1[ti][tj][r];
                float u = acc2[ti][tj][r];
                float hv = g / (1.f + expf(-g)) * u;
                Hout[(size_t)cr * N + nn] = f2b(hv);
            }
        }
    }
}

// =======================================================================
// MERGED fc2: grid (16, 16, NEXP+1). z<NEXP: routed (A=h, K=INTERS,
// C=yexp slot t*6+k, weight w); z==NEXP: shared (A=hs, K=SINTER, C=out,
// weight 1). Epilogue is a plain store for both.
// =======================================================================
__global__ __launch_bounds__(256, 2) void fc2_merged(
    const unsigned short* __restrict__ h, const unsigned short* __restrict__ hs,
    const unsigned short* __restrict__ w22b, const unsigned short* __restrict__ sw2b,
    float* __restrict__ yexp, float* __restrict__ out,
    const int* __restrict__ counts, const int* __restrict__ toklist,
    const float* __restrict__ wgts)
{
    constexpr int BM = 128, BN = 128, BK = 64, LDK = 64;
    __shared__ unsigned short As[BM * LDK];
    __shared__ unsigned short Bs[BN * LDK];
    __shared__ int   aRowS[BM];
    __shared__ int   cRowS[BM];
    __shared__ float cWS[BM];

    const int tid = threadIdx.x;
    const int e   = blockIdx.z;
    const bool SH = (e == NEXP);
    const int K   = SH ? SINTER : INTERS;
    const int n0  = blockIdx.x * BN;          // N = DIMSZ, all x active
    const int m0  = blockIdx.y * BM;
    const int M   = SH ? T_TOK : counts[e];
    if (m0 >= M) return;

    const unsigned short* Asrc = SH ? hs : h;   // row stride == K for both
    const unsigned short* B = SH ? sw2b : (w22b + (size_t)e * DIMSZ * INTERS);
    float* C = SH ? out : yexp;

    if (tid < BM) {
        int r = m0 + tid;
        if (SH) { aRowS[tid] = r; cRowS[tid] = r; cWS[tid] = 1.f; }
        else if (r < M) {
            int ent = toklist[e * T_TOK + r];
            int slot = (ent >> 3) * NTOPK + (ent & 7);
            aRowS[tid] = slot; cRowS[tid] = slot;
            cWS[tid] = wgts[e * T_TOK + r];
        } else { aRowS[tid] = 0; cRowS[tid] = -1; cWS[tid] = 0.f; }
    }
    __syncthreads();

    f32x4 acc[4][4] = {};

    const int wave = tid >> 6;
    const int lane = tid & 63;
    const int wm = (wave >> 1) * 64;
    const int wn = (wave & 1) * 64;
    const int lm = lane & 15;
    const int quad = lane >> 4;

    const unsigned short *aP[4], *bP[4];
    {
        const int l8 = lane >> 3;
        const int sg = (lane & 7) ^ l8;
        #pragma unroll
        for (int i = 0; i < 4; ++i) {
            const int c = wave * 4 + i;
            const int r = c * 8 + l8;
            aP[i] = Asrc + (size_t)aRowS[r] * K + sg * 8;
            bP[i] = B    + (size_t)(n0 + r) * K + sg * 8;
        }
    }

    for (int k0 = 0; k0 < K; k0 += BK) {
        #pragma unroll
        for (int i = 0; i < 4; ++i) {
            const int c = wave * 4 + i;
            gl_lds16(aP[i] + k0, &As[c * 512]);
            gl_lds16(bP[i] + k0, &Bs[c * 512]);
        }
        __syncthreads();
        #pragma unroll
        for (int kh = 0; kh < 2; ++kh) {
            const int soff = (((kh << 2) | quad) ^ (lm & 7)) << 3;
            bf16x8 af[4], bfr[4];
            #pragma unroll
            for (int ti = 0; ti < 4; ++ti)
                af[ti] = *(const bf16x8*)&As[(wm + ti * 16 + lm) * LDK + soff];
            #pragma unroll
            for (int tj = 0; tj < 4; ++tj)
                bfr[tj] = *(const bf16x8*)&Bs[(wn + tj * 16 + lm) * LDK + soff];
            #pragma unroll
            for (int ti = 0; ti < 4; ++ti)
                #pragma unroll
                for (int tj = 0; tj < 4; ++tj)
                    acc[ti][tj] = __builtin_amdgcn_mfma_f32_16x16x32_bf16(
                        af[ti], bfr[tj], acc[ti][tj], 0, 0, 0);
        }
        __syncthreads();
    }

    #pragma unroll
    for (int ti = 0; ti < 4; ++ti) {
        #pragma unroll
        for (int r = 0; r < 4; ++r) {
            int lrow = wm + ti * 16 + quad * 4 + r;
            int cr = cRowS[lrow];
            if (cr < 0) continue;
            #pragma unroll
            for (int tj = 0; tj < 4; ++tj) {
                int nn = n0 + wn + tj * 16 + lm;
                C[(size_t)cr * DIMSZ + nn] = acc[ti][tj][r] * cWS[lrow];
            }
        }
    }
}

// ---------------- combine: out[t,:] += sum_k yexp[t*6+k,:] ----------------
__global__ __launch_bounds__(256) void combine_kernel(
    const float4* __restrict__ yexp, float4* __restrict__ out, int n4)
{
    const int D4 = DIMSZ / 4;   // 512
    int stride = gridDim.x * blockDim.x;
    for (int i = blockIdx.x * blockDim.x + threadIdx.x; i < n4; i += stride) {
        int t = i / D4, d4 = i - t * D4;
        const float4* r = yexp + (size_t)t * NTOPK * D4 + d4;
        float4 a = out[i];
        #pragma unroll
        for (int k = 0; k < NTOPK; ++k) {
            float4 s = r[(size_t)k * D4];
            a.x += s.x; a.y += s.y; a.z += s.z; a.w += s.w;
        }
        out[i] = a;
    }
}

// =======================================================================
// FALLBACK (workspace too small for bf16 mirrors): fp32-weight path
// =======================================================================
template <bool GROUPED>
__global__ __launch_bounds__(256) void fc1_fb(
    const unsigned short* __restrict__ A,
    const float* __restrict__ B1t, const float* __restrict__ B2t,
    unsigned short* __restrict__ H, int N, int K, int M_fixed,
    const int* __restrict__ counts, const int* __restrict__ toklist)
{
    constexpr int BM = 128, BN = 128, BK = 64, LDK = 72;
    __shared__ unsigned short As[BM * LDK];
    __shared__ unsigned short B1s[BN * LDK];
    __shared__ unsigned short B2s[BN * LDK];
    __shared__ int aRowS[BM];
    __shared__ int cRowS[BM];

    const int tid = threadIdx.x;
    const int e  = blockIdx.z;
    const int m0 = blockIdx.y * BM;
    const int n0 = blockIdx.x * BN;

    int M;
    const float *B1, *B2;
    if constexpr (GROUPED) {
        M = counts[e];
        if (m0 >= M) return;
        B1 = B1t + (size_t)e * N * K;
        B2 = B2t + (size_t)e * N * K;
    } else { M = M_fixed; B1 = B1t; B2 = B2t; }

    if (tid < BM) {
        int r = m0 + tid;
        if constexpr (GROUPED) {
            if (r < M) {
                int ent = toklist[e * T_TOK + r];
                int t = ent >> 3, k = ent & 7;
                aRowS[tid] = t; cRowS[tid] = t * NTOPK + k;
            } else { aRowS[tid] = 0; cRowS[tid] = -1; }
        } else { aRowS[tid] = r; cRowS[tid] = (r < M) ? r : -1; }
    }
    __syncthreads();

    f32x4 acc1[4][4] = {};
    f32x4 acc2[4][4] = {};
    const int wave = tid >> 6, lane = tid & 63;
    const int wm = (wave >> 1) * 64, wn = (wave & 1) * 64;
    const int lm = lane & 15, quad = lane >> 4;

    for (int k0 = 0; k0 < K; k0 += BK) {
        #pragma unroll
        for (int i = 0; i < 4; ++i) {
            int lin = tid + i * 256;
            int row = lin >> 3, cq = lin & 7;
            *(float4*)&As[row * LDK + cq * 8] =
                *(const float4*)(A + (size_t)aRowS[row] * K + k0 + cq * 8);
        }
        #pragma unroll
        for (int i = 0; i < 8; ++i) {
            int lin = tid + i * 256;
            int row = lin >> 4, cq = lin & 15;
            size_t boff = (size_t)(n0 + row) * K + k0 + cq * 4;
            float4 v1 = *(const float4*)(B1 + boff);
            float4 v2 = *(const float4*)(B2 + boff);
            ushort4 o1, o2;
            o1.x = f2b(v1.x); o1.y = f2b(v1.y); o1.z = f2b(v1.z); o1.w = f2b(v1.w);
            o2.x = f2b(v2.x); o2.y = f2b(v2.y); o2.z = f2b(v2.z); o2.w = f2b(v2.w);
            *(ushort4*)&B1s[row * LDK + cq * 4] = o1;
            *(ushort4*)&B2s[row * LDK + cq * 4] = o2;
        }
        __syncthreads();
        #pragma unroll
        for (int kk = 0; kk < BK; kk += 32) {
            bf16x8 af[4], b1f[4], b2f[4];
            #pragma unroll
            for (int ti = 0; ti < 4; ++ti)
                af[ti] = *(const bf16x8*)&As[(wm + ti * 16 + lm) * LDK + kk + quad * 8];
            #pragma unroll
            for (int tj = 0; tj < 4; ++tj) {
                b1f[tj] = *(const bf16x8*)&B1s[(wn + tj * 16 + lm) * LDK + kk + quad * 8];
                b2f[tj] = *(const bf16x8*)&B2s[(wn + tj * 16 + lm) * LDK + kk + quad * 8];
            }
            #pragma unroll
            for (int ti = 0; ti < 4; ++ti)
                #pragma unroll
                for (int tj = 0; tj < 4; ++tj) {
                    acc1[ti][tj] = __builtin_amdgcn_mfma_f32_16x16x32_bf16(
                        af[ti], b1f[tj], acc1[ti][tj], 0, 0, 0);
                    acc2[ti][tj] = __builtin_amdgcn_mfma_f32_16x16x32_bf16(
                        af[ti], b2f[tj], acc2[ti][tj], 0, 0, 0);
                }
        }
        __syncthreads();
    }

    #pragma unroll
    for (int ti = 0; ti < 4; ++ti) {
        #pragma unroll
        for (int r = 0; r < 4; ++r) {
            int lrow = wm + ti * 16 + quad * 4 + r;
            int cr = cRowS[lrow];
            if (cr < 0) continue;
            #pragma unroll
            for (int tj = 0; tj < 4; ++tj) {
                int nn = n0 + wn + tj * 16 + lm;
                float g = acc1[ti][tj][r];
                float u = acc2[ti][tj][r];
                float hv = g / (1.f + expf(-g)) * u;
                H[(size_t)cr * N + nn] = f2b(hv);
            }
        }
    }
}

#define SHARED_F32  1
#define GROUP_FC2   3

template <int MODE>
__global__ __launch_bounds__(256) void gemm_fb(
    const unsigned short* __restrict__ A, const float* __restrict__ Bt,
    float* __restrict__ Cf, int N, int K, int M_fixed,
    const int* __restrict__ counts, const int* __restrict__ toklist,
    const float* __restrict__ wgts)
{
    constexpr int BM = 128, BN = 128, BK = 64, LDK = 72;
    __shared__ unsigned short As[BM * LDK];
    __shared__ unsigned short Bs[BN * LDK];
    __shared__ int   aRowS[BM];
    __shared__ int   cRowS[BM];
    __shared__ float cWS[BM];

    const int tid = threadIdx.x;
    const int e  = blockIdx.z;
    const int m0 = blockIdx.y * BM;
    const int n0 = blockIdx.x * BN;

    int M;
    const float* B;
    if constexpr (MODE == GROUP_FC2) {
        M = counts[e];
        if (m0 >= M) return;
        B = Bt + (size_t)e * N * K;
    } else { M = M_fixed; B = Bt; }

    if (tid < BM) {
        int r = m0 + tid;
        if constexpr (MODE == GROUP_FC2) {
            if (r < M) {
                int ent = toklist[e * T_TOK + r];
                int t = ent >> 3, k = ent & 7;
                aRowS[tid] = t * NTOPK + k; cRowS[tid] = t;
                cWS[tid] = wgts[e * T_TOK + r];
            } else { aRowS[tid] = 0; cRowS[tid] = -1; cWS[tid] = 0.f; }
        } else { aRowS[tid] = r; cRowS[tid] = (r < M) ? r : -1; cWS[tid] = 0.f; }
    }
    __syncthreads();

    f32x4 acc[4][4] = {};
    const int wave = tid >> 6, lane = tid & 63;
    const int wm = (wave >> 1) * 64, wn = (wave & 1) * 64;
    const int lm = lane & 15, quad = lane >> 4;

    for (int k0 = 0; k0 < K; k0 += BK) {
        #pragma unroll
        for (int i = 0; i < 4; ++i) {
            int lin = tid + i * 256;
            int row = lin >> 3, cq = lin & 7;
            *(float4*)&As[row * LDK + cq * 8] =
                *(const float4*)(A + (size_t)aRowS[row] * K + k0 + cq * 8);
        }
        #pragma unroll
        for (int i = 0; i < 8; ++i) {
            int lin = tid + i * 256;
            int row = lin >> 4, cq = lin & 15;
            float4 v = *(const float4*)(B + (size_t)(n0 + row) * K + k0 + cq * 4);
            ushort4 o;
            o.x = f2b(v.x); o.y = f2b(v.y); o.z = f2b(v.z); o.w = f2b(v.w);
            *(ushort4*)&Bs[row * LDK + cq * 4] = o;
        }
        __syncthreads();
        #pragma unroll
        for (int kk = 0; kk < BK; kk += 32) {
            bf16x8 af[4], bfr[4];
            #pragma unroll
            for (int ti = 0; ti < 4; ++ti)
                af[ti] = *(const bf16x8*)&As[(wm + ti * 16 + lm) * LDK + kk + quad * 8];
            #pragma unroll
            for (int tj = 0; tj < 4; ++tj)
                bfr[tj] = *(const bf16x8*)&Bs[(wn + tj * 16 + lm) * LDK + kk + quad * 8];
            #pragma unroll
            for (int ti = 0; ti < 4; ++ti)
                #pragma unroll
                for (int tj = 0; tj < 4; ++tj)
                    acc[ti][tj] = __builtin_amdgcn_mfma_f32_16x16x32_bf16(
                        af[ti], bfr[tj], acc[ti][tj], 0, 0, 0);
        }
        __syncthreads();
    }

    #pragma unroll
    for (int ti = 0; ti < 4; ++ti) {
        #pragma unroll
        for (int r = 0; r < 4; ++r) {
            int lrow = wm + ti * 16 + quad * 4 + r;
            int cr = cRowS[lrow];
            if (cr < 0) continue;
            #pragma unroll
            for (int tj = 0; tj < 4; ++tj) {
                int nn = n0 + wn + tj * 16 + lm;
                float v = acc[ti][tj][r];
                if constexpr (MODE == SHARED_F32)
                    Cf[(size_t)cr * N + nn] = v;
                else
                    atomicAdd(&Cf[(size_t)cr * N + nn], v * cWS[lrow]);
            }
        }
    }
}

extern "C" void kernel_launch(void* const* d_in, const int* in_sizes, int n_in,
                              void* d_out, int out_size, void* d_ws, size_t ws_size,
                              hipStream_t stream)
{
    const float* x   = (const float*)d_in[0];
    const float* gw  = (const float*)d_in[1];
    const float* w11 = (const float*)d_in[2];
    const float* w33 = (const float*)d_in[3];
    const float* w22 = (const float*)d_in[4];
    const float* sw1 = (const float*)d_in[5];
    const float* sw2 = (const float*)d_in[6];
    const float* sw3 = (const float*)d_in[7];
    float* out = (float*)d_out;

    char* ws = (char*)d_ws;
    size_t off = 0;
    auto alloc = [&](size_t b) { void* p = ws + off; off = (off + b + 255) & ~(size_t)255; return p; };
    int*            counts  = (int*)alloc(NEXP * 4);
    int*            toklist = (int*)alloc((size_t)NEXP * T_TOK * 4);
    float*          wgts    = (float*)alloc((size_t)NEXP * T_TOK * 4);
    float*          scores  = (float*)alloc((size_t)T_TOK * NEXP * 4);
    unsigned short* xb      = (unsigned short*)alloc((size_t)T_TOK * DIMSZ * 2);
    unsigned short* h       = (unsigned short*)alloc((size_t)T_TOK * NTOPK * INTERS * 2);
    unsigned short* hs      = (unsigned short*)alloc((size_t)T_TOK * SINTER * 2);

    const size_t nW = (size_t)NEXP * INTERS * DIMSZ;
    const size_t nS = (size_t)SINTER * DIMSZ;
    const size_t yBytes = (size_t)T_TOK * NTOPK * DIMSZ * 4;
    const size_t needed = 3 * (nW * 2) + 3 * (nS * 2) + yBytes + 8 * 256;
    const bool FAST = (off + needed) <= ws_size;

    hipMemsetAsync(counts, 0, NEXP * 4, stream);

    const int n4x = T_TOK * DIMSZ / 4;

    if (FAST) {
        unsigned short* w11b = (unsigned short*)alloc(nW * 2);
        unsigned short* w33b = (unsigned short*)alloc(nW * 2);
        unsigned short* w22b = (unsigned short*)alloc(nW * 2);
        unsigned short* sw1b = (unsigned short*)alloc(nS * 2);
        unsigned short* sw3b = (unsigned short*)alloc(nS * 2);
        unsigned short* sw2b = (unsigned short*)alloc(nS * 2);
        float*          yexp = (float*)alloc(yBytes);

        CvtJobs jobs;
        jobs.src[0] = (const float4*)x;   jobs.dst[0] = (ushort4*)xb;   jobs.n4[0] = n4x;
        jobs.src[1] = (const float4*)w11; jobs.dst[1] = (ushort4*)w11b; jobs.n4[1] = (int)(nW / 4);
        jobs.src[2] = (const float4*)w33; jobs.dst[2] = (ushort4*)w33b; jobs.n4[2] = (int)(nW / 4);
        jobs.src[3] = (const float4*)w22; jobs.dst[3] = (ushort4*)w22b; jobs.n4[3] = (int)(nW / 4);
        jobs.src[4] = (const float4*)sw1; jobs.dst[4] = (ushort4*)sw1b; jobs.n4[4] = (int)(nS / 4);
        jobs.src[5] = (const float4*)sw3; jobs.dst[5] = (ushort4*)sw3b; jobs.n4[5] = (int)(nS / 4);
        jobs.src[6] = (const float4*)sw2; jobs.dst[6] = (ushort4*)sw2b; jobs.n4[6] = (int)(nS / 4);
        cvt_multi<<<2048, 256, 0, stream>>>(jobs);

        gate_scores_kernel<<<T_TOK / SCT, 256, 0, stream>>>(x, gw, scores);
        topk_kernel<<<(T_TOK + 255) / 256, 256, 0, stream>>>(scores, counts, toklist, wgts);

        fc1_merged<<<dim3(SINTER / 128, T_TOK / 128, NEXP + 1), 256, 0, stream>>>(
            xb, w11b, w33b, sw1b, sw3b, h, hs, counts, toklist);
        fc2_merged<<<dim3(DIMSZ / 128, T_TOK / 128, NEXP + 1), 256, 0, stream>>>(
            h, hs, w22b, sw2b, yexp, out, counts, toklist, wgts);
        combine_kernel<<<2048, 256, 0, stream>>>((const float4*)yexp, (float4*)out, n4x);
    } else {
        cvt_f2b<<<4096, 256, 0, stream>>>((const float4*)x, (ushort4*)xb, n4x);
        gate_scores_kernel<<<T_TOK / SCT, 256, 0, stream>>>(x, gw, scores);
        topk_kernel<<<(T_TOK + 255) / 256, 256, 0, stream>>>(scores, counts, toklist, wgts);

        fc1_fb<false><<<dim3(SINTER / 128, T_TOK / 128, 1), 256, 0, stream>>>(
            xb, sw1, sw3, hs, SINTER, DIMSZ, T_TOK, nullptr, nullptr);
        gemm_fb<SHARED_F32><<<dim3(DIMSZ / 128, T_TOK / 128, 1), 256, 0, stream>>>(
            hs, sw2, out, DIMSZ, SINTER, T_TOK, nullptr, nullptr, nullptr);
        fc1_fb<true><<<dim3(INTERS / 128, T_TOK / 128, NEXP), 256, 0, stream>>>(
            xb, w11, w33, h, INTERS, DIMSZ, 0, counts, toklist);
        gemm_fb<GROUP_FC2><<<dim3(DIMSZ / 128, T_TOK / 128, NEXP), 256, 0, stream>>>(
            h, w22, out, DIMSZ, INTERS, 0, counts, toklist, wgts);
    }
}

// Round 4
// 1288.906 us; speedup vs baseline: 1.0476x; 1.0476x over previous
//
#include <hip/hip_runtime.h>
#include <hip/hip_bf16.h>

#define T_TOK  2048
#define DIMSZ  2048
#define NEXP   32
#define INTERS 1024
#define SINTER 2048
#define NTOPK  6

typedef __bf16 bf16x8 __attribute__((ext_vector_type(8)));
typedef float  f32x4  __attribute__((ext_vector_type(4)));

__device__ __forceinline__ unsigned short f2b(float f) {
    __hip_bfloat16 h = __float2bfloat16(f);
    return __builtin_bit_cast(unsigned short, h);
}

// async global->LDS, 16B per lane. LDS dest is wave-uniform base + lane*16.
__device__ __forceinline__ void gl_lds16(const unsigned short* g, unsigned short* l) {
    __builtin_amdgcn_global_load_lds(
        (const __attribute__((address_space(1))) void*)g,
        (__attribute__((address_space(3))) void*)l, 16, 0, 0);
}

// ---------------- f32 -> bf16: single kernel, 7 tensors ----------------
struct CvtJobs {
    const float4* src[7];
    ushort4*      dst[7];
    int           n4[7];
};
__global__ __launch_bounds__(256) void cvt_multi(CvtJobs jobs) {
    const int gtid = blockIdx.x * blockDim.x + threadIdx.x;
    const int gstride = gridDim.x * blockDim.x;
    #pragma unroll
    for (int j = 0; j < 7; ++j) {
        const float4* __restrict__ s = jobs.src[j];
        ushort4* __restrict__ d = jobs.dst[j];
        const int n4 = jobs.n4[j];
        for (int i = gtid; i < n4; i += gstride) {
            float4 v = s[i];
            ushort4 o;
            o.x = f2b(v.x); o.y = f2b(v.y); o.z = f2b(v.z); o.w = f2b(v.w);
            d[i] = o;
        }
    }
}

// single-tensor cvt (fallback path: x only)
__global__ void cvt_f2b(const float4* __restrict__ src, ushort4* __restrict__ dst, int n4) {
    int stride = gridDim.x * blockDim.x;
    for (int i = blockIdx.x * blockDim.x + threadIdx.x; i < n4; i += stride) {
        float4 v = src[i];
        ushort4 o;
        o.x = f2b(v.x); o.y = f2b(v.y); o.z = f2b(v.z); o.w = f2b(v.w);
        dst[i] = o;
    }
}

// ---------------- gate scores: scores[T,E] = sigmoid(x @ gw^T), fp32 ----------------
#define SCT 8
#define SCK 128
__global__ __launch_bounds__(256) void gate_scores_kernel(
    const float* __restrict__ x, const float* __restrict__ gw, float* __restrict__ scores)
{
    __shared__ float xs[SCT * SCK];            // 8 x 128
    __shared__ float gs[NEXP * (SCK + 1)];     // 32 x 129 (pad: conflict-free)
    const int t0 = blockIdx.x * SCT;
    const int tid = threadIdx.x;
    const int tl = tid >> 5, e = tid & 31;
    float acc = 0.f;
    for (int k0 = 0; k0 < DIMSZ; k0 += SCK) {
        {
            int row = tid >> 5, d4 = tid & 31;
            *(float4*)&xs[row * SCK + d4 * 4] =
                *(const float4*)&x[(size_t)(t0 + row) * DIMSZ + k0 + d4 * 4];
        }
        #pragma unroll
        for (int i = 0; i < 4; ++i) {
            int lin = tid + i * 256;
            int row = lin >> 5, d4 = lin & 31;
            float4 v = *(const float4*)&gw[(size_t)row * DIMSZ + k0 + d4 * 4];
            float* dst = &gs[row * (SCK + 1) + d4 * 4];
            dst[0] = v.x; dst[1] = v.y; dst[2] = v.z; dst[3] = v.w;
        }
        __syncthreads();
        #pragma unroll 8
        for (int d = 0; d < SCK; ++d)
            acc += xs[tl * SCK + d] * gs[e * (SCK + 1) + d];
        __syncthreads();
    }
    scores[(size_t)(t0 + tl) * NEXP + e] = 1.f / (1.f + expf(-acc));
}

// ---------------- top-k routing (one thread per token) ----------------
__global__ __launch_bounds__(256) void topk_kernel(
    const float* __restrict__ scores,
    int* __restrict__ counts, int* __restrict__ toklist, float* __restrict__ wgts)
{
    int t = blockIdx.x * 256 + threadIdx.x;
    if (t >= T_TOK) return;
    float sc[NEXP];
    #pragma unroll
    for (int e = 0; e < NEXP; ++e) sc[e] = scores[(size_t)t * NEXP + e];

    float gsc[8];
    #pragma unroll
    for (int g = 0; g < 8; ++g) {
        float m = sc[4 * g];
        #pragma unroll
        for (int j = 1; j < 4; ++j) m = fmaxf(m, sc[4 * g + j]);
        gsc[g] = m;
    }
    bool gsel[8] = {false, false, false, false, false, false, false, false};
    for (int it = 0; it < 4; ++it) {
        int bi = -1; float bv = -1e30f;
        #pragma unroll
        for (int g = 0; g < 8; ++g)
            if (!gsel[g] && gsc[g] > bv) { bv = gsc[g]; bi = g; }
        gsel[bi] = true;
    }
    bool esel[NEXP];
    #pragma unroll
    for (int e = 0; e < NEXP; ++e) esel[e] = false;
    int   idx[NTOPK];
    float w[NTOPK];
    float sum = 0.f;
    for (int it = 0; it < NTOPK; ++it) {
        int bi = -1; float bv = -1e30f;
        #pragma unroll
        for (int e = 0; e < NEXP; ++e) {
            if (!gsel[e >> 2] || esel[e]) continue;
            if (sc[e] > bv) { bv = sc[e]; bi = e; }
        }
        esel[bi] = true; idx[it] = bi; w[it] = bv; sum += bv;
    }
    float scale = 2.5f / sum;
    for (int k = 0; k < NTOPK; ++k) {
        int e = idx[k];
        int s = atomicAdd(&counts[e], 1);
        toklist[e * T_TOK + s] = (t << 3) | k;
        wgts[e * T_TOK + s]   = w[k] * scale;
    }
}

// =======================================================================
// fc1_mix: 1-D grid of 1280 blocks. Every 5th block is a shared-expert
// tile (256 total, 16x16 over [T_TOK, SINTER]); the rest decode a routed
// tile id via a prefix walk over counts[] (<=127 y-tiles x 8 x-tiles).
// This interleaves shared and routed tiles in DISPATCH ORDER so the
// 1-block/CU shared phase overlaps with the 3-block/CU routed phase.
// H = silu(A@B1^T) * (A@B2^T), bf16 out. gl_lds + both-sides XOR swizzle.
// =======================================================================
__global__ __launch_bounds__(256, 2) void fc1_mix(
    const unsigned short* __restrict__ A,
    const unsigned short* __restrict__ w11b, const unsigned short* __restrict__ w33b,
    const unsigned short* __restrict__ sw1b, const unsigned short* __restrict__ sw3b,
    unsigned short* __restrict__ h, unsigned short* __restrict__ hs,
    const int* __restrict__ counts, const int* __restrict__ toklist)
{
    constexpr int BM = 128, BN = 128, BK = 64, LDK = 64, K = DIMSZ;
    __shared__ unsigned short As[BM * LDK];
    __shared__ unsigned short B1s[BN * LDK];
    __shared__ unsigned short B2s[BN * LDK];
    __shared__ int aRowS[BM];
    __shared__ int cRowS[BM];
    __shared__ int map[4];   // {isShared, e, ytile, xtile}

    const int tid = threadIdx.x;
    if (tid == 0) {
        const int wgid = blockIdx.x;
        const int s = wgid % 5;
        if (s == 4) {
            const int sid = wgid / 5;            // [0,256)
            map[0] = 1; map[1] = NEXP; map[2] = sid >> 4; map[3] = sid & 15;
        } else {
            const int rid = wgid - wgid / 5;     // routed tile id
            const int xt = rid & 7, ty = rid >> 3;
            int acc2 = 0, fe = -1, fy = 0;
            #pragma unroll
            for (int e2 = 0; e2 < NEXP; ++e2) {
                const int nt = (counts[e2] + 127) >> 7;
                if (fe < 0 && ty < acc2 + nt) { fe = e2; fy = ty - acc2; }
                acc2 += nt;
            }
            map[0] = 0; map[1] = fe; map[2] = fy; map[3] = xt;
        }
    }
    __syncthreads();
    const bool SH = (map[0] != 0);
    const int e  = map[1];
    if (!SH && e < 0) return;            // beyond total routed tiles (uniform)
    const int m0 = map[2] * BM;
    const int n0 = map[3] * BN;
    const int N  = SH ? SINTER : INTERS;
    const int M  = SH ? T_TOK : counts[e];

    const size_t eoff = SH ? 0 : (size_t)e * INTERS * DIMSZ;
    const unsigned short* B1 = (SH ? sw1b : w11b) + eoff;
    const unsigned short* B2 = (SH ? sw3b : w33b) + eoff;
    unsigned short* Hout = SH ? hs : h;

    if (tid < BM) {
        int r = m0 + tid;
        if (SH) { aRowS[tid] = r; cRowS[tid] = r; }
        else if (r < M) {
            int ent = toklist[e * T_TOK + r];
            int t = ent >> 3, k = ent & 7;
            aRowS[tid] = t; cRowS[tid] = t * NTOPK + k;
        } else { aRowS[tid] = 0; cRowS[tid] = -1; }
    }
    __syncthreads();

    f32x4 acc1[4][4] = {};
    f32x4 acc2v[4][4] = {};

    const int wave = tid >> 6;
    const int lane = tid & 63;
    const int wm = (wave >> 1) * 64;
    const int wn = (wave & 1) * 64;
    const int lm = lane & 15;
    const int quad = lane >> 4;

    // per-lane pre-swizzled source pointers (4 chunks of 8 rows each)
    const unsigned short *aP[4], *b1P[4], *b2P[4];
    {
        const int l8 = lane >> 3;             // row within chunk (0..7)
        const int sg = (lane & 7) ^ l8;       // pre-swizzled 16B slot within row
        #pragma unroll
        for (int i = 0; i < 4; ++i) {
            const int c = wave * 4 + i;       // chunk 0..15, rows 8c..8c+7
            const int r = c * 8 + l8;
            aP[i]  = A  + (size_t)aRowS[r] * K + sg * 8;
            b1P[i] = B1 + (size_t)(n0 + r) * K + sg * 8;
            b2P[i] = B2 + (size_t)(n0 + r) * K + sg * 8;
        }
    }

    for (int k0 = 0; k0 < K; k0 += BK) {
        #pragma unroll
        for (int i = 0; i < 4; ++i) {
            const int c = wave * 4 + i;
            gl_lds16(aP[i]  + k0, &As [c * 512]);
            gl_lds16(b1P[i] + k0, &B1s[c * 512]);
            gl_lds16(b2P[i] + k0, &B2s[c * 512]);
        }
        __syncthreads();   // drains vmcnt(0) -> gl_lds data visible
        #pragma unroll
        for (int kh = 0; kh < 2; ++kh) {
            const int soff = (((kh << 2) | quad) ^ (lm & 7)) << 3;
            bf16x8 af[4], bf1[4], bf2[4];
            #pragma unroll
            for (int ti = 0; ti < 4; ++ti)
                af[ti] = *(const bf16x8*)&As[(wm + ti * 16 + lm) * LDK + soff];
            #pragma unroll
            for (int tj = 0; tj < 4; ++tj) {
                bf1[tj] = *(const bf16x8*)&B1s[(wn + tj * 16 + lm) * LDK + soff];
                bf2[tj] = *(const bf16x8*)&B2s[(wn + tj * 16 + lm) * LDK + soff];
            }
            #pragma unroll
            for (int ti = 0; ti < 4; ++ti)
                #pragma unroll
                for (int tj = 0; tj < 4; ++tj) {
                    acc1[ti][tj] = __builtin_amdgcn_mfma_f32_16x16x32_bf16(
                        af[ti], bf1[tj], acc1[ti][tj], 0, 0, 0);
                    acc2v[ti][tj] = __builtin_amdgcn_mfma_f32_16x16x32_bf16(
                        af[ti], bf2[tj], acc2v[ti][tj], 0, 0, 0);
                }
        }
        __syncthreads();
    }

    #pragma unroll
    for (int ti = 0; ti < 4; ++ti) {
        #pragma unroll
        for (int r = 0; r < 4; ++r) {
            int lrow = wm + ti * 16 + quad * 4 + r;
            int cr = cRowS[lrow];
            if (cr < 0) continue;
            #pragma unroll
            for (int tj = 0; tj < 4; ++tj) {
                int nn = n0 + wn + tj * 16 + lm;
                float g = acc1[ti][tj][r];
                float u = acc2v[ti][tj][r];
                float hv = g / (1.f + expf(-g)) * u;
                Hout[(size_t)cr * N + nn] = f2b(hv);
            }
        }
    }
}

// =======================================================================
// fc2_mix: 1-D grid of 2304 blocks; every 9th is a shared tile (256,
// 16x16 over [T_TOK, DIMSZ], A=hs, K=SINTER, C=out). Others decode a
// routed tile (<=127 y-tiles x 16 x-tiles; A=h, K=INTERS, C=yexp slot).
// =======================================================================
__global__ __launch_bounds__(256, 2) void fc2_mix(
    const unsigned short* __restrict__ h, const unsigned short* __restrict__ hs,
    const unsigned short* __restrict__ w22b, const unsigned short* __restrict__ sw2b,
    float* __restrict__ yexp, float* __restrict__ out,
    const int* __restrict__ counts, const int* __restrict__ toklist,
    const float* __restrict__ wgts)
{
    constexpr int BM = 128, BN = 128, BK = 64, LDK = 64;
    __shared__ unsigned short As[BM * LDK];
    __shared__ unsigned short Bs[BN * LDK];
    __shared__ int   aRowS[BM];
    __shared__ int   cRowS[BM];
    __shared__ float cWS[BM];
    __shared__ int   map[4];

    const int tid = threadIdx.x;
    if (tid == 0) {
        const int wgid = blockIdx.x;
        const int s = wgid % 9;
        if (s == 8) {
            const int sid = wgid / 9;            // [0,256)
            map[0] = 1; map[1] = NEXP; map[2] = sid >> 4; map[3] = sid & 15;
        } else {
            const int rid = wgid - wgid / 9;
            const int xt = rid & 15, ty = rid >> 4;
            int acc2 = 0, fe = -1, fy = 0;
            #pragma unroll
            for (int e2 = 0; e2 < NEXP; ++e2) {
                const int nt = (counts[e2] + 127) >> 7;
                if (fe < 0 && ty < acc2 + nt) { fe = e2; fy = ty - acc2; }
                acc2 += nt;
            }
            map[0] = 0; map[1] = fe; map[2] = fy; map[3] = xt;
        }
    }
    __syncthreads();
    const bool SH = (map[0] != 0);
    const int e  = map[1];
    if (!SH && e < 0) return;
    const int m0 = map[2] * BM;
    const int n0 = map[3] * BN;
    const int K  = SH ? SINTER : INTERS;
    const int M  = SH ? T_TOK : counts[e];

    const unsigned short* Asrc = SH ? hs : h;   // row stride == K for both
    const unsigned short* B = SH ? sw2b : (w22b + (size_t)e * DIMSZ * INTERS);
    float* C = SH ? out : yexp;

    if (tid < BM) {
        int r = m0 + tid;
        if (SH) { aRowS[tid] = r; cRowS[tid] = r; cWS[tid] = 1.f; }
        else if (r < M) {
            int ent = toklist[e * T_TOK + r];
            int slot = (ent >> 3) * NTOPK + (ent & 7);
            aRowS[tid] = slot; cRowS[tid] = slot;
            cWS[tid] = wgts[e * T_TOK + r];
        } else { aRowS[tid] = 0; cRowS[tid] = -1; cWS[tid] = 0.f; }
    }
    __syncthreads();

    f32x4 acc[4][4] = {};

    const int wave = tid >> 6;
    const int lane = tid & 63;
    const int wm = (wave >> 1) * 64;
    const int wn = (wave & 1) * 64;
    const int lm = lane & 15;
    const int quad = lane >> 4;

    const unsigned short *aP[4], *bP[4];
    {
        const int l8 = lane >> 3;
        const int sg = (lane & 7) ^ l8;
        #pragma unroll
        for (int i = 0; i < 4; ++i) {
            const int c = wave * 4 + i;
            const int r = c * 8 + l8;
            aP[i] = Asrc + (size_t)aRowS[r] * K + sg * 8;
            bP[i] = B    + (size_t)(n0 + r) * K + sg * 8;
        }
    }

    for (int k0 = 0; k0 < K; k0 += BK) {
        #pragma unroll
        for (int i = 0; i < 4; ++i) {
            const int c = wave * 4 + i;
            gl_lds16(aP[i] + k0, &As[c * 512]);
            gl_lds16(bP[i] + k0, &Bs[c * 512]);
        }
        __syncthreads();
        #pragma unroll
        for (int kh = 0; kh < 2; ++kh) {
            const int soff = (((kh << 2) | quad) ^ (lm & 7)) << 3;
            bf16x8 af[4], bfr[4];
            #pragma unroll
            for (int ti = 0; ti < 4; ++ti)
                af[ti] = *(const bf16x8*)&As[(wm + ti * 16 + lm) * LDK + soff];
            #pragma unroll
            for (int tj = 0; tj < 4; ++tj)
                bfr[tj] = *(const bf16x8*)&Bs[(wn + tj * 16 + lm) * LDK + soff];
            #pragma unroll
            for (int ti = 0; ti < 4; ++ti)
                #pragma unroll
                for (int tj = 0; tj < 4; ++tj)
                    acc[ti][tj] = __builtin_amdgcn_mfma_f32_16x16x32_bf16(
                        af[ti], bfr[tj], acc[ti][tj], 0, 0, 0);
        }
        __syncthreads();
    }

    #pragma unroll
    for (int ti = 0; ti < 4; ++ti) {
        #pragma unroll
        for (int r = 0; r < 4; ++r) {
            int lrow = wm + ti * 16 + quad * 4 + r;
            int cr = cRowS[lrow];
            if (cr < 0) continue;
            #pragma unroll
            for (int tj = 0; tj < 4; ++tj) {
                int nn = n0 + wn + tj * 16 + lm;
                C[(size_t)cr * DIMSZ + nn] = acc[ti][tj][r] * cWS[lrow];
            }
        }
    }
}

// ---------------- combine: out[t,:] += sum_k yexp[t*6+k,:] ----------------
__global__ __launch_bounds__(256) void combine_kernel(
    const float4* __restrict__ yexp, float4* __restrict__ out, int n4)
{
    const int D4 = DIMSZ / 4;   // 512
    int stride = gridDim.x * blockDim.x;
    for (int i = blockIdx.x * blockDim.x + threadIdx.x; i < n4; i += stride) {
        int t = i / D4, d4 = i - t * D4;
        const float4* r = yexp + (size_t)t * NTOPK * D4 + d4;
        float4 a = out[i];
        #pragma unroll
        for (int k = 0; k < NTOPK; ++k) {
            float4 s = r[(size_t)k * D4];
            a.x += s.x; a.y += s.y; a.z += s.z; a.w += s.w;
        }
        out[i] = a;
    }
}

// =======================================================================
// FALLBACK (workspace too small for bf16 mirrors): fp32-weight path
// =======================================================================
template <bool GROUPED>
__global__ __launch_bounds__(256) void fc1_fb(
    const unsigned short* __restrict__ A,
    const float* __restrict__ B1t, const float* __restrict__ B2t,
    unsigned short* __restrict__ H, int N, int K, int M_fixed,
    const int* __restrict__ counts, const int* __restrict__ toklist)
{
    constexpr int BM = 128, BN = 128, BK = 64, LDK = 72;
    __shared__ unsigned short As[BM * LDK];
    __shared__ unsigned short B1s[BN * LDK];
    __shared__ unsigned short B2s[BN * LDK];
    __shared__ int aRowS[BM];
    __shared__ int cRowS[BM];

    const int tid = threadIdx.x;
    const int e  = blockIdx.z;
    const int m0 = blockIdx.y * BM;
    const int n0 = blockIdx.x * BN;

    int M;
    const float *B1, *B2;
    if constexpr (GROUPED) {
        M = counts[e];
        if (m0 >= M) return;
        B1 = B1t + (size_t)e * N * K;
        B2 = B2t + (size_t)e * N * K;
    } else { M = M_fixed; B1 = B1t; B2 = B2t; }

    if (tid < BM) {
        int r = m0 + tid;
        if constexpr (GROUPED) {
            if (r < M) {
                int ent = toklist[e * T_TOK + r];
                int t = ent >> 3, k = ent & 7;
                aRowS[tid] = t; cRowS[tid] = t * NTOPK + k;
            } else { aRowS[tid] = 0; cRowS[tid] = -1; }
        } else { aRowS[tid] = r; cRowS[tid] = (r < M) ? r : -1; }
    }
    __syncthreads();

    f32x4 acc1[4][4] = {};
    f32x4 acc2[4][4] = {};
    const int wave = tid >> 6, lane = tid & 63;
    const int wm = (wave >> 1) * 64, wn = (wave & 1) * 64;
    const int lm = lane & 15, quad = lane >> 4;

    for (int k0 = 0; k0 < K; k0 += BK) {
        #pragma unroll
        for (int i = 0; i < 4; ++i) {
            int lin = tid + i * 256;
            int row = lin >> 3, cq = lin & 7;
            *(float4*)&As[row * LDK + cq * 8] =
                *(const float4*)(A + (size_t)aRowS[row] * K + k0 + cq * 8);
        }
        #pragma unroll
        for (int i = 0; i < 8; ++i) {
            int lin = tid + i * 256;
            int row = lin >> 4, cq = lin & 15;
            size_t boff = (size_t)(n0 + row) * K + k0 + cq * 4;
            float4 v1 = *(const float4*)(B1 + boff);
            float4 v2 = *(const float4*)(B2 + boff);
            ushort4 o1, o2;
            o1.x = f2b(v1.x); o1.y = f2b(v1.y); o1.z = f2b(v1.z); o1.w = f2b(v1.w);
            o2.x = f2b(v2.x); o2.y = f2b(v2.y); o2.z = f2b(v2.z); o2.w = f2b(v2.w);
            *(ushort4*)&B1s[row * LDK + cq * 4] = o1;
            *(ushort4*)&B2s[row * LDK + cq * 4] = o2;
        }
        __syncthreads();
        #pragma unroll
        for (int kk = 0; kk < BK; kk += 32) {
            bf16x8 af[4], b1f[4], b2f[4];
            #pragma unroll
            for (int ti = 0; ti < 4; ++ti)
                af[ti] = *(const bf16x8*)&As[(wm + ti * 16 + lm) * LDK + kk + quad * 8];
            #pragma unroll
            for (int tj = 0; tj < 4; ++tj) {
                b1f[tj] = *(const bf16x8*)&B1s[(wn + tj * 16 + lm) * LDK + kk + quad * 8];
                b2f[tj] = *(const bf16x8*)&B2s[(wn + tj * 16 + lm) * LDK + kk + quad * 8];
            }
            #pragma unroll
            for (int ti = 0; ti < 4; ++ti)
                #pragma unroll
                for (int tj = 0; tj < 4; ++tj) {
                    acc1[ti][tj] = __builtin_amdgcn_mfma_f32_16x16x32_bf16(
                        af[ti], b1f[tj], acc1[ti][tj], 0, 0, 0);
                    acc2[ti][tj] = __builtin_amdgcn_mfma_f32_16x16x32_bf16(
                        af[ti], b2f[tj], acc2[ti][tj], 0, 0, 0);
                }
        }
        __syncthreads();
    }

    #pragma unroll
    for (int ti = 0; ti < 4; ++ti) {
        #pragma unroll
        for (int r = 0; r < 4; ++r) {
            int lrow = wm + ti * 16 + quad * 4 + r;
            int cr = cRowS[lrow];
            if (cr < 0) continue;
            #pragma unroll
            for (int tj = 0; tj < 4; ++tj) {
                int nn = n0 + wn + tj * 16 + lm;
                float g = acc1[ti][tj][r];
                float u = acc2[ti][tj][r];
                float hv = g / (1.f + expf(-g)) * u;
                H[(size_t)cr * N + nn] = f2b(hv);
            }
        }
    }
}

#define SHARED_F32  1
#define GROUP_FC2   3

template <int MODE>
__global__ __launch_bounds__(256) void gemm_fb(
    const unsigned short* __restrict__ A, const float* __restrict__ Bt,
    float* __restrict__ Cf, int N, int K, int M_fixed,
    const int* __restrict__ counts, const int* __restrict__ toklist,
    const float* __restrict__ wgts)
{
    constexpr int BM = 128, BN = 128, BK = 64, LDK = 72;
    __shared__ unsigned short As[BM * LDK];
    __shared__ unsigned short Bs[BN * LDK];
    __shared__ int   aRowS[BM];
    __shared__ int   cRowS[BM];
    __shared__ float cWS[BM];

    const int tid = threadIdx.x;
    const int e  = blockIdx.z;
    const int m0 = blockIdx.y * BM;
    const int n0 = blockIdx.x * BN;

    int M;
    const float* B;
    if constexpr (MODE == GROUP_FC2) {
        M = counts[e];
        if (m0 >= M) return;
        B = Bt + (size_t)e * N * K;
    } else { M = M_fixed; B = Bt; }

    if (tid < BM) {
        int r = m0 + tid;
        if constexpr (MODE == GROUP_FC2) {
            if (r < M) {
                int ent = toklist[e * T_TOK + r];
                int t = ent >> 3, k = ent & 7;
                aRowS[tid] = t * NTOPK + k; cRowS[tid] = t;
                cWS[tid] = wgts[e * T_TOK + r];
            } else { aRowS[tid] = 0; cRowS[tid] = -1; cWS[tid] = 0.f; }
        } else { aRowS[tid] = r; cRowS[tid] = (r < M) ? r : -1; cWS[tid] = 0.f; }
    }
    __syncthreads();

    f32x4 acc[4][4] = {};
    const int wave = tid >> 6, lane = tid & 63;
    const int wm = (wave >> 1) * 64, wn = (wave & 1) * 64;
    const int lm = lane & 15, quad = lane >> 4;

    for (int k0 = 0; k0 < K; k0 += BK) {
        #pragma unroll
        for (int i = 0; i < 4; ++i) {
            int lin = tid + i * 256;
            int row = lin >> 3, cq = lin & 7;
            *(float4*)&As[row * LDK + cq * 8] =
                *(const float4*)(A + (size_t)aRowS[row] * K + k0 + cq * 8);
        }
        #pragma unroll
        for (int i = 0; i < 8; ++i) {
            int lin = tid + i * 256;
            int row = lin >> 4, cq = lin & 15;
            float4 v = *(const float4*)(B + (size_t)(n0 + row) * K + k0 + cq * 4);
            ushort4 o;
            o.x = f2b(v.x); o.y = f2b(v.y); o.z = f2b(v.z); o.w = f2b(v.w);
            *(ushort4*)&Bs[row * LDK + cq * 4] = o;
        }
        __syncthreads();
        #pragma unroll
        for (int kk = 0; kk < BK; kk += 32) {
            bf16x8 af[4], bfr[4];
            #pragma unroll
            for (int ti = 0; ti < 4; ++ti)
                af[ti] = *(const bf16x8*)&As[(wm + ti * 16 + lm) * LDK + kk + quad * 8];
            #pragma unroll
            for (int tj = 0; tj < 4; ++tj)
                bfr[tj] = *(const bf16x8*)&Bs[(wn + tj * 16 + lm) * LDK + kk + quad * 8];
            #pragma unroll
            for (int ti = 0; ti < 4; ++ti)
                #pragma unroll
                for (int tj = 0; tj < 4; ++tj)
                    acc[ti][tj] = __builtin_amdgcn_mfma_f32_16x16x32_bf16(
                        af[ti], bfr[tj], acc[ti][tj], 0, 0, 0);
        }
        __syncthreads();
    }

    #pragma unroll
    for (int ti = 0; ti < 4; ++ti) {
        #pragma unroll
        for (int r = 0; r < 4; ++r) {
            int lrow = wm + ti * 16 + quad * 4 + r;
            int cr = cRowS[lrow];
            if (cr < 0) continue;
            #pragma unroll
            for (int tj = 0; tj < 4; ++tj) {
                int nn = n0 + wn + tj * 16 + lm;
                float v = acc[ti][tj][r];
                if constexpr (MODE == SHARED_F32)
                    Cf[(size_t)cr * N + nn] = v;
                else
                    atomicAdd(&Cf[(size_t)cr * N + nn], v * cWS[lrow]);
            }
        }
    }
}

extern "C" void kernel_launch(void* const* d_in, const int* in_sizes, int n_in,
                              void* d_out, int out_size, void* d_ws, size_t ws_size,
                              hipStream_t stream)
{
    const float* x   = (const float*)d_in[0];
    const float* gw  = (const float*)d_in[1];
    const float* w11 = (const float*)d_in[2];
    const float* w33 = (const float*)d_in[3];
    const float* w22 = (const float*)d_in[4];
    const float* sw1 = (const float*)d_in[5];
    const float* sw2 = (const float*)d_in[6];
    const float* sw3 = (const float*)d_in[7];
    float* out = (float*)d_out;

    char* ws = (char*)d_ws;
    size_t off = 0;
    auto alloc = [&](size_t b) { void* p = ws + off; off = (off + b + 255) & ~(size_t)255; return p; };
    int*            counts  = (int*)alloc(NEXP * 4);
    int*            toklist = (int*)alloc((size_t)NEXP * T_TOK * 4);
    float*          wgts    = (float*)alloc((size_t)NEXP * T_TOK * 4);
    float*          scores  = (float*)alloc((size_t)T_TOK * NEXP * 4);
    unsigned short* xb      = (unsigned short*)alloc((size_t)T_TOK * DIMSZ * 2);
    unsigned short* h       = (unsigned short*)alloc((size_t)T_TOK * NTOPK * INTERS * 2);
    unsigned short* hs      = (unsigned short*)alloc((size_t)T_TOK * SINTER * 2);

    const size_t nW = (size_t)NEXP * INTERS * DIMSZ;
    const size_t nS = (size_t)SINTER * DIMSZ;
    const size_t yBytes = (size_t)T_TOK * NTOPK * DIMSZ * 4;
    const size_t needed = 3 * (nW * 2) + 3 * (nS * 2) + yBytes + 8 * 256;
    const bool FAST = (off + needed) <= ws_size;

    hipMemsetAsync(counts, 0, NEXP * 4, stream);

    const int n4x = T_TOK * DIMSZ / 4;

    if (FAST) {
        unsigned short* w11b = (unsigned short*)alloc(nW * 2);
        unsigned short* w33b = (unsigned short*)alloc(nW * 2);
        unsigned short* w22b = (unsigned short*)alloc(nW * 2);
        unsigned short* sw1b = (unsigned short*)alloc(nS * 2);
        unsigned short* sw3b = (unsigned short*)alloc(nS * 2);
        unsigned short* sw2b = (unsigned short*)alloc(nS * 2);
        float*          yexp = (float*)alloc(yBytes);

        CvtJobs jobs;
        jobs.src[0] = (const float4*)x;   jobs.dst[0] = (ushort4*)xb;   jobs.n4[0] = n4x;
        jobs.src[1] = (const float4*)w11; jobs.dst[1] = (ushort4*)w11b; jobs.n4[1] = (int)(nW / 4);
        jobs.src[2] = (const float4*)w33; jobs.dst[2] = (ushort4*)w33b; jobs.n4[2] = (int)(nW / 4);
        jobs.src[3] = (const float4*)w22; jobs.dst[3] = (ushort4*)w22b; jobs.n4[3] = (int)(nW / 4);
        jobs.src[4] = (const float4*)sw1; jobs.dst[4] = (ushort4*)sw1b; jobs.n4[4] = (int)(nS / 4);
        jobs.src[5] = (const float4*)sw3; jobs.dst[5] = (ushort4*)sw3b; jobs.n4[5] = (int)(nS / 4);
        jobs.src[6] = (const float4*)sw2; jobs.dst[6] = (ushort4*)sw2b; jobs.n4[6] = (int)(nS / 4);
        cvt_multi<<<4096, 256, 0, stream>>>(jobs);

        gate_scores_kernel<<<T_TOK / SCT, 256, 0, stream>>>(x, gw, scores);
        topk_kernel<<<(T_TOK + 255) / 256, 256, 0, stream>>>(scores, counts, toklist, wgts);

        // 1280 = 256 shared tiles * 5 (every 5th block shared, rest routed)
        fc1_mix<<<1280, 256, 0, stream>>>(
            xb, w11b, w33b, sw1b, sw3b, h, hs, counts, toklist);
        // 2304 = 256 shared tiles * 9
        fc2_mix<<<2304, 256, 0, stream>>>(
            h, hs, w22b, sw2b, yexp, out, counts, toklist, wgts);
        combine_kernel<<<2048, 256, 0, stream>>>((const float4*)yexp, (float4*)out, n4x);
    } else {
        cvt_f2b<<<4096, 256, 0, stream>>>((const float4*)x, (ushort4*)xb, n4x);
        gate_scores_kernel<<<T_TOK / SCT, 256, 0, stream>>>(x, gw, scores);
        topk_kernel<<<(T_TOK + 255) / 256, 256, 0, stream>>>(scores, counts, toklist, wgts);

        fc1_fb<false><<<dim3(SINTER / 128, T_TOK / 128, 1), 256, 0, stream>>>(
            xb, sw1, sw3, hs, SINTER, DIMSZ, T_TOK, nullptr, nullptr);
        gemm_fb<SHARED_F32><<<dim3(DIMSZ / 128, T_TOK / 128, 1), 256, 0, stream>>>(
            hs, sw2, out, DIMSZ, SINTER, T_TOK, nullptr, nullptr, nullptr);
        fc1_fb<true><<<dim3(INTERS / 128, T_TOK / 128, NEXP), 256, 0, stream>>>(
            xb, w11, w33, h, INTERS, DIMSZ, 0, counts, toklist);
        gemm_fb<GROUP_FC2><<<dim3(DIMSZ / 128, T_TOK / 128, NEXP), 256, 0, stream>>>(
            h, w22, out, DIMSZ, INTERS, 0, counts, toklist, wgts);
    }
}

// Round 5
// 1220.929 us; speedup vs baseline: 1.1059x; 1.0557x over previous
//
#include <hip/hip_runtime.h>
#include <hip/hip_bf16.h>

#define T_TOK  2048
#define DIMSZ  2048
#define NEXP   32
#define INTERS 1024
#define SINTER 2048
#define NTOPK  6

typedef __bf16 bf16x8 __attribute__((ext_vector_type(8)));
typedef float  f32x4  __attribute__((ext_vector_type(4)));
typedef unsigned short u16x8 __attribute__((ext_vector_type(8)));

__device__ __forceinline__ unsigned short f2b(float f) {
    __hip_bfloat16 h = __float2bfloat16(f);
    return __builtin_bit_cast(unsigned short, h);
}

// async global->LDS, 16B per lane. LDS dest is wave-uniform base + lane*16.
__device__ __forceinline__ void gl_lds16(const unsigned short* g, unsigned short* l) {
    __builtin_amdgcn_global_load_lds(
        (const __attribute__((address_space(1))) void*)g,
        (__attribute__((address_space(3))) void*)l, 16, 0, 0);
}

// ---------------- f32 -> bf16: single kernel, 7 tensors, 16B stores ----------------
struct CvtJobs {
    const float4*   src[7];
    unsigned short* dst[7];
    int             n8[7];   // elements/8
};
__global__ __launch_bounds__(256) void cvt_multi(CvtJobs jobs) {
    const int gtid = blockIdx.x * blockDim.x + threadIdx.x;
    const int gstride = gridDim.x * blockDim.x;
    #pragma unroll
    for (int j = 0; j < 7; ++j) {
        const float4* __restrict__ s = jobs.src[j];
        unsigned short* __restrict__ d = jobs.dst[j];
        const int n8 = jobs.n8[j];
        for (int i = gtid; i < n8; i += gstride) {
            float4 a = s[2 * i];
            float4 b = s[2 * i + 1];
            u16x8 o;
            o[0] = f2b(a.x); o[1] = f2b(a.y); o[2] = f2b(a.z); o[3] = f2b(a.w);
            o[4] = f2b(b.x); o[5] = f2b(b.y); o[6] = f2b(b.z); o[7] = f2b(b.w);
            *(u16x8*)&d[(size_t)i * 8] = o;
        }
    }
}

// single-tensor cvt (fallback path: x only)
__global__ void cvt_f2b(const float4* __restrict__ src, ushort4* __restrict__ dst, int n4) {
    int stride = gridDim.x * blockDim.x;
    for (int i = blockIdx.x * blockDim.x + threadIdx.x; i < n4; i += stride) {
        float4 v = src[i];
        ushort4 o;
        o.x = f2b(v.x); o.y = f2b(v.y); o.z = f2b(v.z); o.w = f2b(v.w);
        dst[i] = o;
    }
}

// ---------------- gate scores: scores[T,E] = sigmoid(x @ gw^T), fp32 ----------------
#define SCT 8
#define SCK 128
__global__ __launch_bounds__(256) void gate_scores_kernel(
    const float* __restrict__ x, const float* __restrict__ gw, float* __restrict__ scores)
{
    __shared__ float xs[SCT * SCK];            // 8 x 128
    __shared__ float gs[NEXP * (SCK + 1)];     // 32 x 129 (pad: conflict-free)
    const int t0 = blockIdx.x * SCT;
    const int tid = threadIdx.x;
    const int tl = tid >> 5, e = tid & 31;
    float acc = 0.f;
    for (int k0 = 0; k0 < DIMSZ; k0 += SCK) {
        {
            int row = tid >> 5, d4 = tid & 31;
            *(float4*)&xs[row * SCK + d4 * 4] =
                *(const float4*)&x[(size_t)(t0 + row) * DIMSZ + k0 + d4 * 4];
        }
        #pragma unroll
        for (int i = 0; i < 4; ++i) {
            int lin = tid + i * 256;
            int row = lin >> 5, d4 = lin & 31;
            float4 v = *(const float4*)&gw[(size_t)row * DIMSZ + k0 + d4 * 4];
            float* dst = &gs[row * (SCK + 1) + d4 * 4];
            dst[0] = v.x; dst[1] = v.y; dst[2] = v.z; dst[3] = v.w;
        }
        __syncthreads();
        #pragma unroll 8
        for (int d = 0; d < SCK; ++d)
            acc += xs[tl * SCK + d] * gs[e * (SCK + 1) + d];
        __syncthreads();
    }
    scores[(size_t)(t0 + tl) * NEXP + e] = 1.f / (1.f + expf(-acc));
}

// ---------------- top-k routing (one thread per token) ----------------
__global__ __launch_bounds__(256) void topk_kernel(
    const float* __restrict__ scores,
    int* __restrict__ counts, int* __restrict__ toklist, float* __restrict__ wgts)
{
    int t = blockIdx.x * 256 + threadIdx.x;
    if (t >= T_TOK) return;
    float sc[NEXP];
    #pragma unroll
    for (int e = 0; e < NEXP; ++e) sc[e] = scores[(size_t)t * NEXP + e];

    float gsc[8];
    #pragma unroll
    for (int g = 0; g < 8; ++g) {
        float m = sc[4 * g];
        #pragma unroll
        for (int j = 1; j < 4; ++j) m = fmaxf(m, sc[4 * g + j]);
        gsc[g] = m;
    }
    bool gsel[8] = {false, false, false, false, false, false, false, false};
    for (int it = 0; it < 4; ++it) {
        int bi = -1; float bv = -1e30f;
        #pragma unroll
        for (int g = 0; g < 8; ++g)
            if (!gsel[g] && gsc[g] > bv) { bv = gsc[g]; bi = g; }
        gsel[bi] = true;
    }
    bool esel[NEXP];
    #pragma unroll
    for (int e = 0; e < NEXP; ++e) esel[e] = false;
    int   idx[NTOPK];
    float w[NTOPK];
    float sum = 0.f;
    for (int it = 0; it < NTOPK; ++it) {
        int bi = -1; float bv = -1e30f;
        #pragma unroll
        for (int e = 0; e < NEXP; ++e) {
            if (!gsel[e >> 2] || esel[e]) continue;
            if (sc[e] > bv) { bv = sc[e]; bi = e; }
        }
        esel[bi] = true; idx[it] = bi; w[it] = bv; sum += bv;
    }
    float scale = 2.5f / sum;
    for (int k = 0; k < NTOPK; ++k) {
        int e = idx[k];
        int s = atomicAdd(&counts[e], 1);
        toklist[e * T_TOK + s] = (t << 3) | k;
        wgts[e * T_TOK + s]   = w[k] * scale;
    }
}

// =======================================================================
// fc1_all: 1-D grid, SHARED TILES FIRST. wgid<256: shared tile (16x16
// over [T_TOK, SINTER]) -- exactly 1 block/CU dispatched first, so the
// low-parallelism shared GEMM overlaps with routed blocks that fill the
// remaining LDS slots. wgid>=256: routed tile, expert-major order
// (x-tile fastest within expert = round-2's proven L2 layout).
// H = silu(A@B1^T) * (A@B2^T), bf16 out. gl_lds + both-sides XOR swizzle.
// =======================================================================
__global__ __launch_bounds__(256, 2) void fc1_all(
    const unsigned short* __restrict__ A,
    const unsigned short* __restrict__ w11b, const unsigned short* __restrict__ w33b,
    const unsigned short* __restrict__ sw1b, const unsigned short* __restrict__ sw3b,
    unsigned short* __restrict__ h, unsigned short* __restrict__ hs,
    const int* __restrict__ counts, const int* __restrict__ toklist)
{
    constexpr int BM = 128, BN = 128, BK = 64, LDK = 64, K = DIMSZ;
    __shared__ unsigned short As[BM * LDK];
    __shared__ unsigned short B1s[BN * LDK];
    __shared__ unsigned short B2s[BN * LDK];
    __shared__ int aRowS[BM];
    __shared__ int cRowS[BM];
    __shared__ int map[4];   // {isShared, e, ytile, xtile}

    const int tid = threadIdx.x;
    if (tid == 0) {
        const int wgid = blockIdx.x;
        if (wgid < 256) {
            map[0] = 1; map[1] = NEXP; map[2] = wgid >> 4; map[3] = wgid & 15;
        } else {
            const int rid = wgid - 256;          // routed tile id
            const int xt = rid & 7, ty = rid >> 3;
            int acc2 = 0, fe = -1, fy = 0;
            #pragma unroll
            for (int e2 = 0; e2 < NEXP; ++e2) {
                const int nt = (counts[e2] + 127) >> 7;
                if (fe < 0 && ty < acc2 + nt) { fe = e2; fy = ty - acc2; }
                acc2 += nt;
            }
            map[0] = 0; map[1] = fe; map[2] = fy; map[3] = xt;
        }
    }
    __syncthreads();
    const bool SH = (map[0] != 0);
    const int e  = map[1];
    if (!SH && e < 0) return;            // beyond total routed tiles (uniform)
    const int m0 = map[2] * BM;
    const int n0 = map[3] * BN;
    const int N  = SH ? SINTER : INTERS;
    const int M  = SH ? T_TOK : counts[e];

    const size_t eoff = SH ? 0 : (size_t)e * INTERS * DIMSZ;
    const unsigned short* B1 = (SH ? sw1b : w11b) + eoff;
    const unsigned short* B2 = (SH ? sw3b : w33b) + eoff;
    unsigned short* Hout = SH ? hs : h;

    if (tid < BM) {
        int r = m0 + tid;
        if (SH) { aRowS[tid] = r; cRowS[tid] = r; }
        else if (r < M) {
            int ent = toklist[e * T_TOK + r];
            int t = ent >> 3, k = ent & 7;
            aRowS[tid] = t; cRowS[tid] = t * NTOPK + k;
        } else { aRowS[tid] = 0; cRowS[tid] = -1; }
    }
    __syncthreads();

    f32x4 acc1[4][4] = {};
    f32x4 acc2v[4][4] = {};

    const int wave = tid >> 6;
    const int lane = tid & 63;
    const int wm = (wave >> 1) * 64;
    const int wn = (wave & 1) * 64;
    const int lm = lane & 15;
    const int quad = lane >> 4;

    // per-lane pre-swizzled source pointers (4 chunks of 8 rows each)
    const unsigned short *aP[4], *b1P[4], *b2P[4];
    {
        const int l8 = lane >> 3;             // row within chunk (0..7)
        const int sg = (lane & 7) ^ l8;       // pre-swizzled 16B slot within row
        #pragma unroll
        for (int i = 0; i < 4; ++i) {
            const int c = wave * 4 + i;       // chunk 0..15, rows 8c..8c+7
            const int r = c * 8 + l8;
            aP[i]  = A  + (size_t)aRowS[r] * K + sg * 8;
            b1P[i] = B1 + (size_t)(n0 + r) * K + sg * 8;
            b2P[i] = B2 + (size_t)(n0 + r) * K + sg * 8;
        }
    }

    for (int k0 = 0; k0 < K; k0 += BK) {
        #pragma unroll
        for (int i = 0; i < 4; ++i) {
            const int c = wave * 4 + i;
            gl_lds16(aP[i]  + k0, &As [c * 512]);
            gl_lds16(b1P[i] + k0, &B1s[c * 512]);
            gl_lds16(b2P[i] + k0, &B2s[c * 512]);
        }
        __syncthreads();   // drains vmcnt(0) -> gl_lds data visible
        #pragma unroll
        for (int kh = 0; kh < 2; ++kh) {
            const int soff = (((kh << 2) | quad) ^ (lm & 7)) << 3;
            bf16x8 af[4], bf1[4], bf2[4];
            #pragma unroll
            for (int ti = 0; ti < 4; ++ti)
                af[ti] = *(const bf16x8*)&As[(wm + ti * 16 + lm) * LDK + soff];
            #pragma unroll
            for (int tj = 0; tj < 4; ++tj) {
                bf1[tj] = *(const bf16x8*)&B1s[(wn + tj * 16 + lm) * LDK + soff];
                bf2[tj] = *(const bf16x8*)&B2s[(wn + tj * 16 + lm) * LDK + soff];
            }
            #pragma unroll
            for (int ti = 0; ti < 4; ++ti)
                #pragma unroll
                for (int tj = 0; tj < 4; ++tj) {
                    acc1[ti][tj] = __builtin_amdgcn_mfma_f32_16x16x32_bf16(
                        af[ti], bf1[tj], acc1[ti][tj], 0, 0, 0);
                    acc2v[ti][tj] = __builtin_amdgcn_mfma_f32_16x16x32_bf16(
                        af[ti], bf2[tj], acc2v[ti][tj], 0, 0, 0);
                }
        }
        __syncthreads();
    }

    #pragma unroll
    for (int ti = 0; ti < 4; ++ti) {
        #pragma unroll
        for (int r = 0; r < 4; ++r) {
            int lrow = wm + ti * 16 + quad * 4 + r;
            int cr = cRowS[lrow];
            if (cr < 0) continue;
            #pragma unroll
            for (int tj = 0; tj < 4; ++tj) {
                int nn = n0 + wn + tj * 16 + lm;
                float g = acc1[ti][tj][r];
                float u = acc2v[ti][tj][r];
                float hv = g / (1.f + expf(-g)) * u;
                Hout[(size_t)cr * N + nn] = f2b(hv);
            }
        }
    }
}

// =======================================================================
// fc2_all: 1-D grid, shared first (wgid<256: A=hs, K=SINTER, C=out;
// these are 2x-work long poles so they start earliest). wgid>=256:
// routed tile (A=h, K=INTERS, C=yexp slot), expert-major, x fastest.
// =======================================================================
__global__ __launch_bounds__(256, 2) void fc2_all(
    const unsigned short* __restrict__ h, const unsigned short* __restrict__ hs,
    const unsigned short* __restrict__ w22b, const unsigned short* __restrict__ sw2b,
    float* __restrict__ yexp, float* __restrict__ out,
    const int* __restrict__ counts, const int* __restrict__ toklist,
    const float* __restrict__ wgts)
{
    constexpr int BM = 128, BN = 128, BK = 64, LDK = 64;
    __shared__ unsigned short As[BM * LDK];
    __shared__ unsigned short Bs[BN * LDK];
    __shared__ int   aRowS[BM];
    __shared__ int   cRowS[BM];
    __shared__ float cWS[BM];
    __shared__ int   map[4];

    const int tid = threadIdx.x;
    if (tid == 0) {
        const int wgid = blockIdx.x;
        if (wgid < 256) {
            map[0] = 1; map[1] = NEXP; map[2] = wgid >> 4; map[3] = wgid & 15;
        } else {
            const int rid = wgid - 256;
            const int xt = rid & 15, ty = rid >> 4;
            int acc2 = 0, fe = -1, fy = 0;
            #pragma unroll
            for (int e2 = 0; e2 < NEXP; ++e2) {
                const int nt = (counts[e2] + 127) >> 7;
                if (fe < 0 && ty < acc2 + nt) { fe = e2; fy = ty - acc2; }
                acc2 += nt;
            }
            map[0] = 0; map[1] = fe; map[2] = fy; map[3] = xt;
        }
    }
    __syncthreads();
    const bool SH = (map[0] != 0);
    const int e  = map[1];
    if (!SH && e < 0) return;
    const int m0 = map[2] * BM;
    const int n0 = map[3] * BN;
    const int K  = SH ? SINTER : INTERS;
    const int M  = SH ? T_TOK : counts[e];

    const unsigned short* Asrc = SH ? hs : h;   // row stride == K for both
    const unsigned short* B = SH ? sw2b : (w22b + (size_t)e * DIMSZ * INTERS);
    float* C = SH ? out : yexp;

    if (tid < BM) {
        int r = m0 + tid;
        if (SH) { aRowS[tid] = r; cRowS[tid] = r; cWS[tid] = 1.f; }
        else if (r < M) {
            int ent = toklist[e * T_TOK + r];
            int slot = (ent >> 3) * NTOPK + (ent & 7);
            aRowS[tid] = slot; cRowS[tid] = slot;
            cWS[tid] = wgts[e * T_TOK + r];
        } else { aRowS[tid] = 0; cRowS[tid] = -1; cWS[tid] = 0.f; }
    }
    __syncthreads();

    f32x4 acc[4][4] = {};

    const int wave = tid >> 6;
    const int lane = tid & 63;
    const int wm = (wave >> 1) * 64;
    const int wn = (wave & 1) * 64;
    const int lm = lane & 15;
    const int quad = lane >> 4;

    const unsigned short *aP[4], *bP[4];
    {
        const int l8 = lane >> 3;
        const int sg = (lane & 7) ^ l8;
        #pragma unroll
        for (int i = 0; i < 4; ++i) {
            const int c = wave * 4 + i;
            const int r = c * 8 + l8;
            aP[i] = Asrc + (size_t)aRowS[r] * K + sg * 8;
            bP[i] = B    + (size_t)(n0 + r) * K + sg * 8;
        }
    }

    for (int k0 = 0; k0 < K; k0 += BK) {
        #pragma unroll
        for (int i = 0; i < 4; ++i) {
            const int c = wave * 4 + i;
            gl_lds16(aP[i] + k0, &As[c * 512]);
            gl_lds16(bP[i] + k0, &Bs[c * 512]);
        }
        __syncthreads();
        #pragma unroll
        for (int kh = 0; kh < 2; ++kh) {
            const int soff = (((kh << 2) | quad) ^ (lm & 7)) << 3;
            bf16x8 af[4], bfr[4];
            #pragma unroll
            for (int ti = 0; ti < 4; ++ti)
                af[ti] = *(const bf16x8*)&As[(wm + ti * 16 + lm) * LDK + soff];
            #pragma unroll
            for (int tj = 0; tj < 4; ++tj)
                bfr[tj] = *(const bf16x8*)&Bs[(wn + tj * 16 + lm) * LDK + soff];
            #pragma unroll
            for (int ti = 0; ti < 4; ++ti)
                #pragma unroll
                for (int tj = 0; tj < 4; ++tj)
                    acc[ti][tj] = __builtin_amdgcn_mfma_f32_16x16x32_bf16(
                        af[ti], bfr[tj], acc[ti][tj], 0, 0, 0);
        }
        __syncthreads();
    }

    #pragma unroll
    for (int ti = 0; ti < 4; ++ti) {
        #pragma unroll
        for (int r = 0; r < 4; ++r) {
            int lrow = wm + ti * 16 + quad * 4 + r;
            int cr = cRowS[lrow];
            if (cr < 0) continue;
            #pragma unroll
            for (int tj = 0; tj < 4; ++tj) {
                int nn = n0 + wn + tj * 16 + lm;
                C[(size_t)cr * DIMSZ + nn] = acc[ti][tj][r] * cWS[lrow];
            }
        }
    }
}

// ---------------- combine: out[t,:] += sum_k yexp[t*6+k,:] ----------------
__global__ __launch_bounds__(256) void combine_kernel(
    const float4* __restrict__ yexp, float4* __restrict__ out, int n4)
{
    const int D4 = DIMSZ / 4;   // 512
    int stride = gridDim.x * blockDim.x;
    for (int i = blockIdx.x * blockDim.x + threadIdx.x; i < n4; i += stride) {
        int t = i / D4, d4 = i - t * D4;
        const float4* r = yexp + (size_t)t * NTOPK * D4 + d4;
        float4 a = out[i];
        #pragma unroll
        for (int k = 0; k < NTOPK; ++k) {
            float4 s = r[(size_t)k * D4];
            a.x += s.x; a.y += s.y; a.z += s.z; a.w += s.w;
        }
        out[i] = a;
    }
}

// =======================================================================
// FALLBACK (workspace too small for bf16 mirrors): fp32-weight path
// =======================================================================
template <bool GROUPED>
__global__ __launch_bounds__(256) void fc1_fb(
    const unsigned short* __restrict__ A,
    const float* __restrict__ B1t, const float* __restrict__ B2t,
    unsigned short* __restrict__ H, int N, int K, int M_fixed,
    const int* __restrict__ counts, const int* __restrict__ toklist)
{
    constexpr int BM = 128, BN = 128, BK = 64, LDK = 72;
    __shared__ unsigned short As[BM * LDK];
    __shared__ unsigned short B1s[BN * LDK];
    __shared__ unsigned short B2s[BN * LDK];
    __shared__ int aRowS[BM];
    __shared__ int cRowS[BM];

    const int tid = threadIdx.x;
    const int e  = blockIdx.z;
    const int m0 = blockIdx.y * BM;
    const int n0 = blockIdx.x * BN;

    int M;
    const float *B1, *B2;
    if constexpr (GROUPED) {
        M = counts[e];
        if (m0 >= M) return;
        B1 = B1t + (size_t)e * N * K;
        B2 = B2t + (size_t)e * N * K;
    } else { M = M_fixed; B1 = B1t; B2 = B2t; }

    if (tid < BM) {
        int r = m0 + tid;
        if constexpr (GROUPED) {
            if (r < M) {
                int ent = toklist[e * T_TOK + r];
                int t = ent >> 3, k = ent & 7;
                aRowS[tid] = t; cRowS[tid] = t * NTOPK + k;
            } else { aRowS[tid] = 0; cRowS[tid] = -1; }
        } else { aRowS[tid] = r; cRowS[tid] = (r < M) ? r : -1; }
    }
    __syncthreads();

    f32x4 acc1[4][4] = {};
    f32x4 acc2[4][4] = {};
    const int wave = tid >> 6, lane = tid & 63;
    const int wm = (wave >> 1) * 64, wn = (wave & 1) * 64;
    const int lm = lane & 15, quad = lane >> 4;

    for (int k0 = 0; k0 < K; k0 += BK) {
        #pragma unroll
        for (int i = 0; i < 4; ++i) {
            int lin = tid + i * 256;
            int row = lin >> 3, cq = lin & 7;
            *(float4*)&As[row * LDK + cq * 8] =
                *(const float4*)(A + (size_t)aRowS[row] * K + k0 + cq * 8);
        }
        #pragma unroll
        for (int i = 0; i < 8; ++i) {
            int lin = tid + i * 256;
            int row = lin >> 4, cq = lin & 15;
            size_t boff = (size_t)(n0 + row) * K + k0 + cq * 4;
            float4 v1 = *(const float4*)(B1 + boff);
            float4 v2 = *(const float4*)(B2 + boff);
            ushort4 o1, o2;
            o1.x = f2b(v1.x); o1.y = f2b(v1.y); o1.z = f2b(v1.z); o1.w = f2b(v1.w);
            o2.x = f2b(v2.x); o2.y = f2b(v2.y); o2.z = f2b(v2.z); o2.w = f2b(v2.w);
            *(ushort4*)&B1s[row * LDK + cq * 4] = o1;
            *(ushort4*)&B2s[row * LDK + cq * 4] = o2;
        }
        __syncthreads();
        #pragma unroll
        for (int kk = 0; kk < BK; kk += 32) {
            bf16x8 af[4], b1f[4], b2f[4];
            #pragma unroll
            for (int ti = 0; ti < 4; ++ti)
                af[ti] = *(const bf16x8*)&As[(wm + ti * 16 + lm) * LDK + kk + quad * 8];
            #pragma unroll
            for (int tj = 0; tj < 4; ++tj) {
                b1f[tj] = *(const bf16x8*)&B1s[(wn + tj * 16 + lm) * LDK + kk + quad * 8];
                b2f[tj] = *(const bf16x8*)&B2s[(wn + tj * 16 + lm) * LDK + kk + quad * 8];
            }
            #pragma unroll
            for (int ti = 0; ti < 4; ++ti)
                #pragma unroll
                for (int tj = 0; tj < 4; ++tj) {
                    acc1[ti][tj] = __builtin_amdgcn_mfma_f32_16x16x32_bf16(
                        af[ti], b1f[tj], acc1[ti][tj], 0, 0, 0);
                    acc2[ti][tj] = __builtin_amdgcn_mfma_f32_16x16x32_bf16(
                        af[ti], b2f[tj], acc2[ti][tj], 0, 0, 0);
                }
        }
        __syncthreads();
    }

    #pragma unroll
    for (int ti = 0; ti < 4; ++ti) {
        #pragma unroll
        for (int r = 0; r < 4; ++r) {
            int lrow = wm + ti * 16 + quad * 4 + r;
            int cr = cRowS[lrow];
            if (cr < 0) continue;
            #pragma unroll
            for (int tj = 0; tj < 4; ++tj) {
                int nn = n0 + wn + tj * 16 + lm;
                float g = acc1[ti][tj][r];
                float u = acc2[ti][tj][r];
                float hv = g / (1.f + expf(-g)) * u;
                H[(size_t)cr * N + nn] = f2b(hv);
            }
        }
    }
}

#define SHARED_F32  1
#define GROUP_FC2   3

template <int MODE>
__global__ __launch_bounds__(256) void gemm_fb(
    const unsigned short* __restrict__ A, const float* __restrict__ Bt,
    float* __restrict__ Cf, int N, int K, int M_fixed,
    const int* __restrict__ counts, const int* __restrict__ toklist,
    const float* __restrict__ wgts)
{
    constexpr int BM = 128, BN = 128, BK = 64, LDK = 72;
    __shared__ unsigned short As[BM * LDK];
    __shared__ unsigned short Bs[BN * LDK];
    __shared__ int   aRowS[BM];
    __shared__ int   cRowS[BM];
    __shared__ float cWS[BM];

    const int tid = threadIdx.x;
    const int e  = blockIdx.z;
    const int m0 = blockIdx.y * BM;
    const int n0 = blockIdx.x * BN;

    int M;
    const float* B;
    if constexpr (MODE == GROUP_FC2) {
        M = counts[e];
        if (m0 >= M) return;
        B = Bt + (size_t)e * N * K;
    } else { M = M_fixed; B = Bt; }

    if (tid < BM) {
        int r = m0 + tid;
        if constexpr (MODE == GROUP_FC2) {
            if (r < M) {
                int ent = toklist[e * T_TOK + r];
                int t = ent >> 3, k = ent & 7;
                aRowS[tid] = t * NTOPK + k; cRowS[tid] = t;
                cWS[tid] = wgts[e * T_TOK + r];
            } else { aRowS[tid] = 0; cRowS[tid] = -1; cWS[tid] = 0.f; }
        } else { aRowS[tid] = r; cRowS[tid] = (r < M) ? r : -1; cWS[tid] = 0.f; }
    }
    __syncthreads();

    f32x4 acc[4][4] = {};
    const int wave = tid >> 6, lane = tid & 63;
    const int wm = (wave >> 1) * 64, wn = (wave & 1) * 64;
    const int lm = lane & 15, quad = lane >> 4;

    for (int k0 = 0; k0 < K; k0 += BK) {
        #pragma unroll
        for (int i = 0; i < 4; ++i) {
            int lin = tid + i * 256;
            int row = lin >> 3, cq = lin & 7;
            *(float4*)&As[row * LDK + cq * 8] =
                *(const float4*)(A + (size_t)aRowS[row] * K + k0 + cq * 8);
        }
        #pragma unroll
        for (int i = 0; i < 8; ++i) {
            int lin = tid + i * 256;
            int row = lin >> 4, cq = lin & 15;
            float4 v = *(const float4*)(B + (size_t)(n0 + row) * K + k0 + cq * 4);
            ushort4 o;
            o.x = f2b(v.x); o.y = f2b(v.y); o.z = f2b(v.z); o.w = f2b(v.w);
            *(ushort4*)&Bs[row * LDK + cq * 4] = o;
        }
        __syncthreads();
        #pragma unroll
        for (int kk = 0; kk < BK; kk += 32) {
            bf16x8 af[4], bfr[4];
            #pragma unroll
            for (int ti = 0; ti < 4; ++ti)
                af[ti] = *(const bf16x8*)&As[(wm + ti * 16 + lm) * LDK + kk + quad * 8];
            #pragma unroll
            for (int tj = 0; tj < 4; ++tj)
                bfr[tj] = *(const bf16x8*)&Bs[(wn + tj * 16 + lm) * LDK + kk + quad * 8];
            #pragma unroll
            for (int ti = 0; ti < 4; ++ti)
                #pragma unroll
                for (int tj = 0; tj < 4; ++tj)
                    acc[ti][tj] = __builtin_amdgcn_mfma_f32_16x16x32_bf16(
                        af[ti], bfr[tj], acc[ti][tj], 0, 0, 0);
        }
        __syncthreads();
    }

    #pragma unroll
    for (int ti = 0; ti < 4; ++ti) {
        #pragma unroll
        for (int r = 0; r < 4; ++r) {
            int lrow = wm + ti * 16 + quad * 4 + r;
            int cr = cRowS[lrow];
            if (cr < 0) continue;
            #pragma unroll
            for (int tj = 0; tj < 4; ++tj) {
                int nn = n0 + wn + tj * 16 + lm;
                float v = acc[ti][tj][r];
                if constexpr (MODE == SHARED_F32)
                    Cf[(size_t)cr * N + nn] = v;
                else
                    atomicAdd(&Cf[(size_t)cr * N + nn], v * cWS[lrow]);
            }
        }
    }
}

extern "C" void kernel_launch(void* const* d_in, const int* in_sizes, int n_in,
                              void* d_out, int out_size, void* d_ws, size_t ws_size,
                              hipStream_t stream)
{
    const float* x   = (const float*)d_in[0];
    const float* gw  = (const float*)d_in[1];
    const float* w11 = (const float*)d_in[2];
    const float* w33 = (const float*)d_in[3];
    const float* w22 = (const float*)d_in[4];
    const float* sw1 = (const float*)d_in[5];
    const float* sw2 = (const float*)d_in[6];
    const float* sw3 = (const float*)d_in[7];
    float* out = (float*)d_out;

    char* ws = (char*)d_ws;
    size_t off = 0;
    auto alloc = [&](size_t b) { void* p = ws + off; off = (off + b + 255) & ~(size_t)255; return p; };
    int*            counts  = (int*)alloc(NEXP * 4);
    int*            toklist = (int*)alloc((size_t)NEXP * T_TOK * 4);
    float*          wgts    = (float*)alloc((size_t)NEXP * T_TOK * 4);
    float*          scores  = (float*)alloc((size_t)T_TOK * NEXP * 4);
    unsigned short* xb      = (unsigned short*)alloc((size_t)T_TOK * DIMSZ * 2);
    unsigned short* h       = (unsigned short*)alloc((size_t)T_TOK * NTOPK * INTERS * 2);
    unsigned short* hs      = (unsigned short*)alloc((size_t)T_TOK * SINTER * 2);

    const size_t nW = (size_t)NEXP * INTERS * DIMSZ;
    const size_t nS = (size_t)SINTER * DIMSZ;
    const size_t yBytes = (size_t)T_TOK * NTOPK * DIMSZ * 4;
    const size_t needed = 3 * (nW * 2) + 3 * (nS * 2) + yBytes + 8 * 256;
    const bool FAST = (off + needed) <= ws_size;

    hipMemsetAsync(counts, 0, NEXP * 4, stream);

    const int n4x = T_TOK * DIMSZ / 4;

    if (FAST) {
        unsigned short* w11b = (unsigned short*)alloc(nW * 2);
        unsigned short* w33b = (unsigned short*)alloc(nW * 2);
        unsigned short* w22b = (unsigned short*)alloc(nW * 2);
        unsigned short* sw1b = (unsigned short*)alloc(nS * 2);
        unsigned short* sw3b = (unsigned short*)alloc(nS * 2);
        unsigned short* sw2b = (unsigned short*)alloc(nS * 2);
        float*          yexp = (float*)alloc(yBytes);

        CvtJobs jobs;
        jobs.src[0] = (const float4*)x;   jobs.dst[0] = xb;   jobs.n8[0] = (int)((size_t)T_TOK * DIMSZ / 8);
        jobs.src[1] = (const float4*)w11; jobs.dst[1] = w11b; jobs.n8[1] = (int)(nW / 8);
        jobs.src[2] = (const float4*)w33; jobs.dst[2] = w33b; jobs.n8[2] = (int)(nW / 8);
        jobs.src[3] = (const float4*)w22; jobs.dst[3] = w22b; jobs.n8[3] = (int)(nW / 8);
        jobs.src[4] = (const float4*)sw1; jobs.dst[4] = sw1b; jobs.n8[4] = (int)(nS / 8);
        jobs.src[5] = (const float4*)sw3; jobs.dst[5] = sw3b; jobs.n8[5] = (int)(nS / 8);
        jobs.src[6] = (const float4*)sw2; jobs.dst[6] = sw2b; jobs.n8[6] = (int)(nS / 8);
        cvt_multi<<<4096, 256, 0, stream>>>(jobs);

        gate_scores_kernel<<<T_TOK / SCT, 256, 0, stream>>>(x, gw, scores);
        topk_kernel<<<(T_TOK + 255) / 256, 256, 0, stream>>>(scores, counts, toklist, wgts);

        // shared tiles first (256 = 1/CU), then routed tiles fill remaining slots
        fc1_all<<<256 + 128 * 8, 256, 0, stream>>>(
            xb, w11b, w33b, sw1b, sw3b, h, hs, counts, toklist);
        fc2_all<<<256 + 128 * 16, 256, 0, stream>>>(
            h, hs, w22b, sw2b, yexp, out, counts, toklist, wgts);
        combine_kernel<<<2048, 256, 0, stream>>>((const float4*)yexp, (float4*)out, n4x);
    } else {
        cvt_f2b<<<4096, 256, 0, stream>>>((const float4*)x, (ushort4*)xb, n4x);
        gate_scores_kernel<<<T_TOK / SCT, 256, 0, stream>>>(x, gw, scores);
        topk_kernel<<<(T_TOK + 255) / 256, 256, 0, stream>>>(scores, counts, toklist, wgts);

        fc1_fb<false><<<dim3(SINTER / 128, T_TOK / 128, 1), 256, 0, stream>>>(
            xb, sw1, sw3, hs, SINTER, DIMSZ, T_TOK, nullptr, nullptr);
        gemm_fb<SHARED_F32><<<dim3(DIMSZ / 128, T_TOK / 128, 1), 256, 0, stream>>>(
            hs, sw2, out, DIMSZ, SINTER, T_TOK, nullptr, nullptr, nullptr);
        fc1_fb<true><<<dim3(INTERS / 128, T_TOK / 128, NEXP), 256, 0, stream>>>(
            xb, w11, w33, h, INTERS, DIMSZ, 0, counts, toklist);
        gemm_fb<GROUP_FC2><<<dim3(DIMSZ / 128, T_TOK / 128, NEXP), 256, 0, stream>>>(
            h, w22, out, DIMSZ, INTERS, 0, counts, toklist, wgts);
    }
}

// Round 6
// 1165.042 us; speedup vs baseline: 1.1590x; 1.0480x over previous
//
#include <hip/hip_runtime.h>
#include <hip/hip_bf16.h>

#define T_TOK  2048
#define DIMSZ  2048
#define NEXP   32
#define INTERS 1024
#define SINTER 2048
#define NTOPK  6

#define N8_W   ((32 * 1024 * 2048) / 8)   // w22 chunks of 8 elems
#define N8_S   ((2048 * 2048) / 8)        // sw2 chunks

typedef __bf16 bf16x8 __attribute__((ext_vector_type(8)));
typedef float  f32x4  __attribute__((ext_vector_type(4)));
typedef unsigned short u16x8 __attribute__((ext_vector_type(8)));

__device__ __forceinline__ unsigned short f2b(float f) {
    __hip_bfloat16 h = __float2bfloat16(f);
    return __builtin_bit_cast(unsigned short, h);
}

// async global->LDS, 16B per lane. LDS dest is wave-uniform base + lane*16.
__device__ __forceinline__ void gl_lds16(const unsigned short* g, unsigned short* l) {
    __builtin_amdgcn_global_load_lds(
        (const __attribute__((address_space(1))) void*)g,
        (__attribute__((address_space(3))) void*)l, 16, 0, 0);
}

// ---- streaming f32->bf16, 2-way unrolled for MLP (both loads in flight) ----
__device__ __forceinline__ void cvt_stream(
    const float4* __restrict__ s, unsigned short* __restrict__ d,
    int n8, int i0, int stride)
{
    int i = i0;
    for (; i + stride < n8; i += 2 * stride) {
        const int i2 = i + stride;
        float4 a0 = s[2 * (size_t)i];
        float4 b0 = s[2 * (size_t)i + 1];
        float4 a1 = s[2 * (size_t)i2];
        float4 b1 = s[2 * (size_t)i2 + 1];
        u16x8 o0, o1;
        o0[0] = f2b(a0.x); o0[1] = f2b(a0.y); o0[2] = f2b(a0.z); o0[3] = f2b(a0.w);
        o0[4] = f2b(b0.x); o0[5] = f2b(b0.y); o0[6] = f2b(b0.z); o0[7] = f2b(b0.w);
        o1[0] = f2b(a1.x); o1[1] = f2b(a1.y); o1[2] = f2b(a1.z); o1[3] = f2b(a1.w);
        o1[4] = f2b(b1.x); o1[5] = f2b(b1.y); o1[6] = f2b(b1.z); o1[7] = f2b(b1.w);
        *(u16x8*)&d[(size_t)i * 8]  = o0;
        *(u16x8*)&d[(size_t)i2 * 8] = o1;
    }
    if (i < n8) {
        float4 a = s[2 * (size_t)i];
        float4 b = s[2 * (size_t)i + 1];
        u16x8 o;
        o[0] = f2b(a.x); o[1] = f2b(a.y); o[2] = f2b(a.z); o[3] = f2b(a.w);
        o[4] = f2b(b.x); o[5] = f2b(b.y); o[6] = f2b(b.z); o[7] = f2b(b.w);
        *(u16x8*)&d[(size_t)i * 8] = o;
    }
}

// ---------------- pre-GEMM conversions: x, w11, w33, sw1, sw3 ----------------
struct CvtJobs5 {
    const float4*   src[5];
    unsigned short* dst[5];
    int             n8[5];
};
__global__ __launch_bounds__(256) void cvt_multi5(CvtJobs5 jobs) {
    const int gtid = blockIdx.x * blockDim.x + threadIdx.x;
    const int gstride = gridDim.x * blockDim.x;
    #pragma unroll
    for (int j = 0; j < 5; ++j)
        cvt_stream(jobs.src[j], jobs.dst[j], jobs.n8[j], gtid, gstride);
}

// single-tensor cvt (fallback path: x only)
__global__ void cvt_f2b(const float4* __restrict__ src, ushort4* __restrict__ dst, int n4) {
    int stride = gridDim.x * blockDim.x;
    for (int i = blockIdx.x * blockDim.x + threadIdx.x; i < n4; i += stride) {
        float4 v = src[i];
        ushort4 o;
        o.x = f2b(v.x); o.y = f2b(v.y); o.z = f2b(v.z); o.w = f2b(v.w);
        dst[i] = o;
    }
}

// ---------------- gate scores: scores[T,E] = sigmoid(x @ gw^T), fp32 ----------------
#define SCT 8
#define SCK 128
__global__ __launch_bounds__(256) void gate_scores_kernel(
    const float* __restrict__ x, const float* __restrict__ gw, float* __restrict__ scores)
{
    __shared__ float xs[SCT * SCK];            // 8 x 128
    __shared__ float gs[NEXP * (SCK + 1)];     // 32 x 129 (pad: conflict-free)
    const int t0 = blockIdx.x * SCT;
    const int tid = threadIdx.x;
    const int tl = tid >> 5, e = tid & 31;
    float acc = 0.f;
    for (int k0 = 0; k0 < DIMSZ; k0 += SCK) {
        {
            int row = tid >> 5, d4 = tid & 31;
            *(float4*)&xs[row * SCK + d4 * 4] =
                *(const float4*)&x[(size_t)(t0 + row) * DIMSZ + k0 + d4 * 4];
        }
        #pragma unroll
        for (int i = 0; i < 4; ++i) {
            int lin = tid + i * 256;
            int row = lin >> 5, d4 = lin & 31;
            float4 v = *(const float4*)&gw[(size_t)row * DIMSZ + k0 + d4 * 4];
            float* dst = &gs[row * (SCK + 1) + d4 * 4];
            dst[0] = v.x; dst[1] = v.y; dst[2] = v.z; dst[3] = v.w;
        }
        __syncthreads();
        #pragma unroll 8
        for (int d = 0; d < SCK; ++d)
            acc += xs[tl * SCK + d] * gs[e * (SCK + 1) + d];
        __syncthreads();
    }
    scores[(size_t)(t0 + tl) * NEXP + e] = 1.f / (1.f + expf(-acc));
}

// ---------------- top-k routing (one thread per token) ----------------
__global__ __launch_bounds__(256) void topk_kernel(
    const float* __restrict__ scores,
    int* __restrict__ counts, int* __restrict__ toklist, float* __restrict__ wgts)
{
    int t = blockIdx.x * 256 + threadIdx.x;
    if (t >= T_TOK) return;
    float sc[NEXP];
    #pragma unroll
    for (int e = 0; e < NEXP; ++e) sc[e] = scores[(size_t)t * NEXP + e];

    float gsc[8];
    #pragma unroll
    for (int g = 0; g < 8; ++g) {
        float m = sc[4 * g];
        #pragma unroll
        for (int j = 1; j < 4; ++j) m = fmaxf(m, sc[4 * g + j]);
        gsc[g] = m;
    }
    bool gsel[8] = {false, false, false, false, false, false, false, false};
    for (int it = 0; it < 4; ++it) {
        int bi = -1; float bv = -1e30f;
        #pragma unroll
        for (int g = 0; g < 8; ++g)
            if (!gsel[g] && gsc[g] > bv) { bv = gsc[g]; bi = g; }
        gsel[bi] = true;
    }
    bool esel[NEXP];
    #pragma unroll
    for (int e = 0; e < NEXP; ++e) esel[e] = false;
    int   idx[NTOPK];
    float w[NTOPK];
    float sum = 0.f;
    for (int it = 0; it < NTOPK; ++it) {
        int bi = -1; float bv = -1e30f;
        #pragma unroll
        for (int e = 0; e < NEXP; ++e) {
            if (!gsel[e >> 2] || esel[e]) continue;
            if (sc[e] > bv) { bv = sc[e]; bi = e; }
        }
        esel[bi] = true; idx[it] = bi; w[it] = bv; sum += bv;
    }
    float scale = 2.5f / sum;
    for (int k = 0; k < NTOPK; ++k) {
        int e = idx[k];
        int s = atomicAdd(&counts[e], 1);
        toklist[e * T_TOK + s] = (t << 3) | k;
        wgts[e * T_TOK + s]   = w[k] * scale;
    }
}

// =======================================================================
// fc1_all: 1-D grid of 256 + 1536 blocks, three roles:
//   wgid < 256           : shared-expert tile (1/CU, dispatched first)
//   r = wgid-256, r%3==2 : cvt worker (512 total) -- converts w22/sw2 to
//                          bf16 using fc1's idle HBM bandwidth (fc1 runs
//                          at ~17% BW). Stream order makes w22b ready
//                          before fc2_all launches.
//   else                 : routed tile, expert-major (rid = r-(r+1)/3)
// H = silu(A@B1^T) * (A@B2^T), bf16 out. gl_lds + both-sides XOR swizzle.
// =======================================================================
__global__ __launch_bounds__(256, 2) void fc1_all(
    const unsigned short* __restrict__ A,
    const unsigned short* __restrict__ w11b, const unsigned short* __restrict__ w33b,
    const unsigned short* __restrict__ sw1b, const unsigned short* __restrict__ sw3b,
    unsigned short* __restrict__ h, unsigned short* __restrict__ hs,
    const int* __restrict__ counts, const int* __restrict__ toklist,
    const float* __restrict__ w22f, const float* __restrict__ sw2f,
    unsigned short* __restrict__ w22b, unsigned short* __restrict__ sw2b)
{
    constexpr int BM = 128, BN = 128, BK = 64, LDK = 64, K = DIMSZ;
    __shared__ unsigned short As[BM * LDK];
    __shared__ unsigned short B1s[BN * LDK];
    __shared__ unsigned short B2s[BN * LDK];
    __shared__ int aRowS[BM];
    __shared__ int cRowS[BM];
    __shared__ int map[4];   // {role(0 routed,1 shared,2 cvt), e|cvtId, ytile, xtile}

    const int tid = threadIdx.x;
    if (tid == 0) {
        const int wgid = blockIdx.x;
        if (wgid < 256) {
            map[0] = 1; map[1] = NEXP; map[2] = wgid >> 4; map[3] = wgid & 15;
        } else {
            const int r = wgid - 256;
            if ((r % 3) == 2) {
                map[0] = 2; map[1] = r / 3; map[2] = 0; map[3] = 0;
            } else {
                const int rid = r - (r + 1) / 3;     // routed tile id
                const int xt = rid & 7, ty = rid >> 3;
                int acc2 = 0, fe = -1, fy = 0;
                #pragma unroll
                for (int e2 = 0; e2 < NEXP; ++e2) {
                    const int nt = (counts[e2] + 127) >> 7;
                    if (fe < 0 && ty < acc2 + nt) { fe = e2; fy = ty - acc2; }
                    acc2 += nt;
                }
                map[0] = 0; map[1] = fe; map[2] = fy; map[3] = xt;
            }
        }
    }
    __syncthreads();
    const int role = map[0];
    if (role == 2) {
        // stream-convert w22 then sw2 (512 worker blocks x 256 threads)
        const int i0 = map[1] * 256 + tid;
        const int stride = 512 * 256;
        cvt_stream((const float4*)w22f, w22b, N8_W, i0, stride);
        cvt_stream((const float4*)sw2f, sw2b, N8_S, i0, stride);
        return;
    }
    const bool SH = (role == 1);
    const int e  = map[1];
    if (!SH && e < 0) return;            // beyond total routed tiles (uniform)
    const int m0 = map[2] * BM;
    const int n0 = map[3] * BN;
    const int N  = SH ? SINTER : INTERS;
    const int M  = SH ? T_TOK : counts[e];

    const size_t eoff = SH ? 0 : (size_t)e * INTERS * DIMSZ;
    const unsigned short* B1 = (SH ? sw1b : w11b) + eoff;
    const unsigned short* B2 = (SH ? sw3b : w33b) + eoff;
    unsigned short* Hout = SH ? hs : h;

    if (tid < BM) {
        int r = m0 + tid;
        if (SH) { aRowS[tid] = r; cRowS[tid] = r; }
        else if (r < M) {
            int ent = toklist[e * T_TOK + r];
            int t = ent >> 3, k = ent & 7;
            aRowS[tid] = t; cRowS[tid] = t * NTOPK + k;
        } else { aRowS[tid] = 0; cRowS[tid] = -1; }
    }
    __syncthreads();

    f32x4 acc1[4][4] = {};
    f32x4 acc2v[4][4] = {};

    const int wave = tid >> 6;
    const int lane = tid & 63;
    const int wm = (wave >> 1) * 64;
    const int wn = (wave & 1) * 64;
    const int lm = lane & 15;
    const int quad = lane >> 4;

    // per-lane pre-swizzled source pointers (4 chunks of 8 rows each)
    const unsigned short *aP[4], *b1P[4], *b2P[4];
    {
        const int l8 = lane >> 3;             // row within chunk (0..7)
        const int sg = (lane & 7) ^ l8;       // pre-swizzled 16B slot within row
        #pragma unroll
        for (int i = 0; i < 4; ++i) {
            const int c = wave * 4 + i;       // chunk 0..15, rows 8c..8c+7
            const int r = c * 8 + l8;
            aP[i]  = A  + (size_t)aRowS[r] * K + sg * 8;
            b1P[i] = B1 + (size_t)(n0 + r) * K + sg * 8;
            b2P[i] = B2 + (size_t)(n0 + r) * K + sg * 8;
        }
    }

    for (int k0 = 0; k0 < K; k0 += BK) {
        #pragma unroll
        for (int i = 0; i < 4; ++i) {
            const int c = wave * 4 + i;
            gl_lds16(aP[i]  + k0, &As [c * 512]);
            gl_lds16(b1P[i] + k0, &B1s[c * 512]);
            gl_lds16(b2P[i] + k0, &B2s[c * 512]);
        }
        __syncthreads();   // drains vmcnt(0) -> gl_lds data visible
        #pragma unroll
        for (int kh = 0; kh < 2; ++kh) {
            const int soff = (((kh << 2) | quad) ^ (lm & 7)) << 3;
            bf16x8 af[4], bf1[4], bf2[4];
            #pragma unroll
            for (int ti = 0; ti < 4; ++ti)
                af[ti] = *(const bf16x8*)&As[(wm + ti * 16 + lm) * LDK + soff];
            #pragma unroll
            for (int tj = 0; tj < 4; ++tj) {
                bf1[tj] = *(const bf16x8*)&B1s[(wn + tj * 16 + lm) * LDK + soff];
                bf2[tj] = *(const bf16x8*)&B2s[(wn + tj * 16 + lm) * LDK + soff];
            }
            #pragma unroll
            for (int ti = 0; ti < 4; ++ti)
                #pragma unroll
                for (int tj = 0; tj < 4; ++tj) {
                    acc1[ti][tj] = __builtin_amdgcn_mfma_f32_16x16x32_bf16(
                        af[ti], bf1[tj], acc1[ti][tj], 0, 0, 0);
                    acc2v[ti][tj] = __builtin_amdgcn_mfma_f32_16x16x32_bf16(
                        af[ti], bf2[tj], acc2v[ti][tj], 0, 0, 0);
                }
        }
        __syncthreads();
    }

    #pragma unroll
    for (int ti = 0; ti < 4; ++ti) {
        #pragma unroll
        for (int r = 0; r < 4; ++r) {
            int lrow = wm + ti * 16 + quad * 4 + r;
            int cr = cRowS[lrow];
            if (cr < 0) continue;
            #pragma unroll
            for (int tj = 0; tj < 4; ++tj) {
                int nn = n0 + wn + tj * 16 + lm;
                float g = acc1[ti][tj][r];
                float u = acc2v[ti][tj][r];
                float hv = g / (1.f + expf(-g)) * u;
                Hout[(size_t)cr * N + nn] = f2b(hv);
            }
        }
    }
}

// =======================================================================
// fc2_all: 1-D grid, shared first (wgid<256: A=hs, K=SINTER, C=out).
// wgid>=256: routed tile (A=h, K=INTERS, C=yexp slot), expert-major.
// =======================================================================
__global__ __launch_bounds__(256, 2) void fc2_all(
    const unsigned short* __restrict__ h, const unsigned short* __restrict__ hs,
    const unsigned short* __restrict__ w22b, const unsigned short* __restrict__ sw2b,
    float* __restrict__ yexp, float* __restrict__ out,
    const int* __restrict__ counts, const int* __restrict__ toklist,
    const float* __restrict__ wgts)
{
    constexpr int BM = 128, BN = 128, BK = 64, LDK = 64;
    __shared__ unsigned short As[BM * LDK];
    __shared__ unsigned short Bs[BN * LDK];
    __shared__ int   aRowS[BM];
    __shared__ int   cRowS[BM];
    __shared__ float cWS[BM];
    __shared__ int   map[4];

    const int tid = threadIdx.x;
    if (tid == 0) {
        const int wgid = blockIdx.x;
        if (wgid < 256) {
            map[0] = 1; map[1] = NEXP; map[2] = wgid >> 4; map[3] = wgid & 15;
        } else {
            const int rid = wgid - 256;
            const int xt = rid & 15, ty = rid >> 4;
            int acc2 = 0, fe = -1, fy = 0;
            #pragma unroll
            for (int e2 = 0; e2 < NEXP; ++e2) {
                const int nt = (counts[e2] + 127) >> 7;
                if (fe < 0 && ty < acc2 + nt) { fe = e2; fy = ty - acc2; }
                acc2 += nt;
            }
            map[0] = 0; map[1] = fe; map[2] = fy; map[3] = xt;
        }
    }
    __syncthreads();
    const bool SH = (map[0] != 0);
    const int e  = map[1];
    if (!SH && e < 0) return;
    const int m0 = map[2] * BM;
    const int n0 = map[3] * BN;
    const int K  = SH ? SINTER : INTERS;
    const int M  = SH ? T_TOK : counts[e];

    const unsigned short* Asrc = SH ? hs : h;   // row stride == K for both
    const unsigned short* B = SH ? sw2b : (w22b + (size_t)e * DIMSZ * INTERS);
    float* C = SH ? out : yexp;

    if (tid < BM) {
        int r = m0 + tid;
        if (SH) { aRowS[tid] = r; cRowS[tid] = r; cWS[tid] = 1.f; }
        else if (r < M) {
            int ent = toklist[e * T_TOK + r];
            int slot = (ent >> 3) * NTOPK + (ent & 7);
            aRowS[tid] = slot; cRowS[tid] = slot;
            cWS[tid] = wgts[e * T_TOK + r];
        } else { aRowS[tid] = 0; cRowS[tid] = -1; cWS[tid] = 0.f; }
    }
    __syncthreads();

    f32x4 acc[4][4] = {};

    const int wave = tid >> 6;
    const int lane = tid & 63;
    const int wm = (wave >> 1) * 64;
    const int wn = (wave & 1) * 64;
    const int lm = lane & 15;
    const int quad = lane >> 4;

    const unsigned short *aP[4], *bP[4];
    {
        const int l8 = lane >> 3;
        const int sg = (lane & 7) ^ l8;
        #pragma unroll
        for (int i = 0; i < 4; ++i) {
            const int c = wave * 4 + i;
            const int r = c * 8 + l8;
            aP[i] = Asrc + (size_t)aRowS[r] * K + sg * 8;
            bP[i] = B    + (size_t)(n0 + r) * K + sg * 8;
        }
    }

    for (int k0 = 0; k0 < K; k0 += BK) {
        #pragma unroll
        for (int i = 0; i < 4; ++i) {
            const int c = wave * 4 + i;
            gl_lds16(aP[i] + k0, &As[c * 512]);
            gl_lds16(bP[i] + k0, &Bs[c * 512]);
        }
        __syncthreads();
        #pragma unroll
        for (int kh = 0; kh < 2; ++kh) {
            const int soff = (((kh << 2) | quad) ^ (lm & 7)) << 3;
            bf16x8 af[4], bfr[4];
            #pragma unroll
            for (int ti = 0; ti < 4; ++ti)
                af[ti] = *(const bf16x8*)&As[(wm + ti * 16 + lm) * LDK + soff];
            #pragma unroll
            for (int tj = 0; tj < 4; ++tj)
                bfr[tj] = *(const bf16x8*)&Bs[(wn + tj * 16 + lm) * LDK + soff];
            #pragma unroll
            for (int ti = 0; ti < 4; ++ti)
                #pragma unroll
                for (int tj = 0; tj < 4; ++tj)
                    acc[ti][tj] = __builtin_amdgcn_mfma_f32_16x16x32_bf16(
                        af[ti], bfr[tj], acc[ti][tj], 0, 0, 0);
        }
        __syncthreads();
    }

    #pragma unroll
    for (int ti = 0; ti < 4; ++ti) {
        #pragma unroll
        for (int r = 0; r < 4; ++r) {
            int lrow = wm + ti * 16 + quad * 4 + r;
            int cr = cRowS[lrow];
            if (cr < 0) continue;
            #pragma unroll
            for (int tj = 0; tj < 4; ++tj) {
                int nn = n0 + wn + tj * 16 + lm;
                C[(size_t)cr * DIMSZ + nn] = acc[ti][tj][r] * cWS[lrow];
            }
        }
    }
}

// ---------------- combine: out[t,:] += sum_k yexp[t*6+k,:] ----------------
__global__ __launch_bounds__(256) void combine_kernel(
    const float4* __restrict__ yexp, float4* __restrict__ out, int n4)
{
    const int D4 = DIMSZ / 4;   // 512
    int stride = gridDim.x * blockDim.x;
    for (int i = blockIdx.x * blockDim.x + threadIdx.x; i < n4; i += stride) {
        int t = i / D4, d4 = i - t * D4;
        const float4* r = yexp + (size_t)t * NTOPK * D4 + d4;
        float4 a = out[i];
        #pragma unroll
        for (int k = 0; k < NTOPK; ++k) {
            float4 s = r[(size_t)k * D4];
            a.x += s.x; a.y += s.y; a.z += s.z; a.w += s.w;
        }
        out[i] = a;
    }
}

// =======================================================================
// FALLBACK (workspace too small for bf16 mirrors): fp32-weight path
// =======================================================================
template <bool GROUPED>
__global__ __launch_bounds__(256) void fc1_fb(
    const unsigned short* __restrict__ A,
    const float* __restrict__ B1t, const float* __restrict__ B2t,
    unsigned short* __restrict__ H, int N, int K, int M_fixed,
    const int* __restrict__ counts, const int* __restrict__ toklist)
{
    constexpr int BM = 128, BN = 128, BK = 64, LDK = 72;
    __shared__ unsigned short As[BM * LDK];
    __shared__ unsigned short B1s[BN * LDK];
    __shared__ unsigned short B2s[BN * LDK];
    __shared__ int aRowS[BM];
    __shared__ int cRowS[BM];

    const int tid = threadIdx.x;
    const int e  = blockIdx.z;
    const int m0 = blockIdx.y * BM;
    const int n0 = blockIdx.x * BN;

    int M;
    const float *B1, *B2;
    if constexpr (GROUPED) {
        M = counts[e];
        if (m0 >= M) return;
        B1 = B1t + (size_t)e * N * K;
        B2 = B2t + (size_t)e * N * K;
    } else { M = M_fixed; B1 = B1t; B2 = B2t; }

    if (tid < BM) {
        int r = m0 + tid;
        if constexpr (GROUPED) {
            if (r < M) {
                int ent = toklist[e * T_TOK + r];
                int t = ent >> 3, k = ent & 7;
                aRowS[tid] = t; cRowS[tid] = t * NTOPK + k;
            } else { aRowS[tid] = 0; cRowS[tid] = -1; }
        } else { aRowS[tid] = r; cRowS[tid] = (r < M) ? r : -1; }
    }
    __syncthreads();

    f32x4 acc1[4][4] = {};
    f32x4 acc2[4][4] = {};
    const int wave = tid >> 6, lane = tid & 63;
    const int wm = (wave >> 1) * 64, wn = (wave & 1) * 64;
    const int lm = lane & 15, quad = lane >> 4;

    for (int k0 = 0; k0 < K; k0 += BK) {
        #pragma unroll
        for (int i = 0; i < 4; ++i) {
            int lin = tid + i * 256;
            int row = lin >> 3, cq = lin & 7;
            *(float4*)&As[row * LDK + cq * 8] =
                *(const float4*)(A + (size_t)aRowS[row] * K + k0 + cq * 8);
        }
        #pragma unroll
        for (int i = 0; i < 8; ++i) {
            int lin = tid + i * 256;
            int row = lin >> 4, cq = lin & 15;
            size_t boff = (size_t)(n0 + row) * K + k0 + cq * 4;
            float4 v1 = *(const float4*)(B1 + boff);
            float4 v2 = *(const float4*)(B2 + boff);
            ushort4 o1, o2;
            o1.x = f2b(v1.x); o1.y = f2b(v1.y); o1.z = f2b(v1.z); o1.w = f2b(v1.w);
            o2.x = f2b(v2.x); o2.y = f2b(v2.y); o2.z = f2b(v2.z); o2.w = f2b(v2.w);
            *(ushort4*)&B1s[row * LDK + cq * 4] = o1;
            *(ushort4*)&B2s[row * LDK + cq * 4] = o2;
        }
        __syncthreads();
        #pragma unroll
        for (int kk = 0; kk < BK; kk += 32) {
            bf16x8 af[4], b1f[4], b2f[4];
            #pragma unroll
            for (int ti = 0; ti < 4; ++ti)
                af[ti] = *(const bf16x8*)&As[(wm + ti * 16 + lm) * LDK + kk + quad * 8];
            #pragma unroll
            for (int tj = 0; tj < 4; ++tj) {
                b1f[tj] = *(const bf16x8*)&B1s[(wn + tj * 16 + lm) * LDK + kk + quad * 8];
                b2f[tj] = *(const bf16x8*)&B2s[(wn + tj * 16 + lm) * LDK + kk + quad * 8];
            }
            #pragma unroll
            for (int ti = 0; ti < 4; ++ti)
                #pragma unroll
                for (int tj = 0; tj < 4; ++tj) {
                    acc1[ti][tj] = __builtin_amdgcn_mfma_f32_16x16x32_bf16(
                        af[ti], b1f[tj], acc1[ti][tj], 0, 0, 0);
                    acc2[ti][tj] = __builtin_amdgcn_mfma_f32_16x16x32_bf16(
                        af[ti], b2f[tj], acc2[ti][tj], 0, 0, 0);
                }
        }
        __syncthreads();
    }

    #pragma unroll
    for (int ti = 0; ti < 4; ++ti) {
        #pragma unroll
        for (int r = 0; r < 4; ++r) {
            int lrow = wm + ti * 16 + quad * 4 + r;
            int cr = cRowS[lrow];
            if (cr < 0) continue;
            #pragma unroll
            for (int tj = 0; tj < 4; ++tj) {
                int nn = n0 + wn + tj * 16 + lm;
                float g = acc1[ti][tj][r];
                float u = acc2[ti][tj][r];
                float hv = g / (1.f + expf(-g)) * u;
                H[(size_t)cr * N + nn] = f2b(hv);
            }
        }
    }
}

#define SHARED_F32  1
#define GROUP_FC2   3

template <int MODE>
__global__ __launch_bounds__(256) void gemm_fb(
    const unsigned short* __restrict__ A, const float* __restrict__ Bt,
    float* __restrict__ Cf, int N, int K, int M_fixed,
    const int* __restrict__ counts, const int* __restrict__ toklist,
    const float* __restrict__ wgts)
{
    constexpr int BM = 128, BN = 128, BK = 64, LDK = 72;
    __shared__ unsigned short As[BM * LDK];
    __shared__ unsigned short Bs[BN * LDK];
    __shared__ int   aRowS[BM];
    __shared__ int   cRowS[BM];
    __shared__ float cWS[BM];

    const int tid = threadIdx.x;
    const int e  = blockIdx.z;
    const int m0 = blockIdx.y * BM;
    const int n0 = blockIdx.x * BN;

    int M;
    const float* B;
    if constexpr (MODE == GROUP_FC2) {
        M = counts[e];
        if (m0 >= M) return;
        B = Bt + (size_t)e * N * K;
    } else { M = M_fixed; B = Bt; }

    if (tid < BM) {
        int r = m0 + tid;
        if constexpr (MODE == GROUP_FC2) {
            if (r < M) {
                int ent = toklist[e * T_TOK + r];
                int t = ent >> 3, k = ent & 7;
                aRowS[tid] = t * NTOPK + k; cRowS[tid] = t;
                cWS[tid] = wgts[e * T_TOK + r];
            } else { aRowS[tid] = 0; cRowS[tid] = -1; cWS[tid] = 0.f; }
        } else { aRowS[tid] = r; cRowS[tid] = (r < M) ? r : -1; cWS[tid] = 0.f; }
    }
    __syncthreads();

    f32x4 acc[4][4] = {};
    const int wave = tid >> 6, lane = tid & 63;
    const int wm = (wave >> 1) * 64, wn = (wave & 1) * 64;
    const int lm = lane & 15, quad = lane >> 4;

    for (int k0 = 0; k0 < K; k0 += BK) {
        #pragma unroll
        for (int i = 0; i < 4; ++i) {
            int lin = tid + i * 256;
            int row = lin >> 3, cq = lin & 7;
            *(float4*)&As[row * LDK + cq * 8] =
                *(const float4*)(A + (size_t)aRowS[row] * K + k0 + cq * 8);
        }
        #pragma unroll
        for (int i = 0; i < 8; ++i) {
            int lin = tid + i * 256;
            int row = lin >> 4, cq = lin & 15;
            float4 v = *(const float4*)(B + (size_t)(n0 + row) * K + k0 + cq * 4);
            ushort4 o;
            o.x = f2b(v.x); o.y = f2b(v.y); o.z = f2b(v.z); o.w = f2b(v.w);
            *(ushort4*)&Bs[row * LDK + cq * 4] = o;
        }
        __syncthreads();
        #pragma unroll
        for (int kk = 0; kk < BK; kk += 32) {
            bf16x8 af[4], bfr[4];
            #pragma unroll
            for (int ti = 0; ti < 4; ++ti)
                af[ti] = *(const bf16x8*)&As[(wm + ti * 16 + lm) * LDK + kk + quad * 8];
            #pragma unroll
            for (int tj = 0; tj < 4; ++tj)
                bfr[tj] = *(const bf16x8*)&Bs[(wn + tj * 16 + lm) * LDK + kk + quad * 8];
            #pragma unroll
            for (int ti = 0; ti < 4; ++ti)
                #pragma unroll
                for (int tj = 0; tj < 4; ++tj)
                    acc[ti][tj] = __builtin_amdgcn_mfma_f32_16x16x32_bf16(
                        af[ti], bfr[tj], acc[ti][tj], 0, 0, 0);
        }
        __syncthreads();
    }

    #pragma unroll
    for (int ti = 0; ti < 4; ++ti) {
        #pragma unroll
        for (int r = 0; r < 4; ++r) {
            int lrow = wm + ti * 16 + quad * 4 + r;
            int cr = cRowS[lrow];
            if (cr < 0) continue;
            #pragma unroll
            for (int tj = 0; tj < 4; ++tj) {
                int nn = n0 + wn + tj * 16 + lm;
                float v = acc[ti][tj][r];
                if constexpr (MODE == SHARED_F32)
                    Cf[(size_t)cr * N + nn] = v;
                else
                    atomicAdd(&Cf[(size_t)cr * N + nn], v * cWS[lrow]);
            }
        }
    }
}

extern "C" void kernel_launch(void* const* d_in, const int* in_sizes, int n_in,
                              void* d_out, int out_size, void* d_ws, size_t ws_size,
                              hipStream_t stream)
{
    const float* x   = (const float*)d_in[0];
    const float* gw  = (const float*)d_in[1];
    const float* w11 = (const float*)d_in[2];
    const float* w33 = (const float*)d_in[3];
    const float* w22 = (const float*)d_in[4];
    const float* sw1 = (const float*)d_in[5];
    const float* sw2 = (const float*)d_in[6];
    const float* sw3 = (const float*)d_in[7];
    float* out = (float*)d_out;

    char* ws = (char*)d_ws;
    size_t off = 0;
    auto alloc = [&](size_t b) { void* p = ws + off; off = (off + b + 255) & ~(size_t)255; return p; };
    int*            counts  = (int*)alloc(NEXP * 4);
    int*            toklist = (int*)alloc((size_t)NEXP * T_TOK * 4);
    float*          wgts    = (float*)alloc((size_t)NEXP * T_TOK * 4);
    float*          scores  = (float*)alloc((size_t)T_TOK * NEXP * 4);
    unsigned short* xb      = (unsigned short*)alloc((size_t)T_TOK * DIMSZ * 2);
    unsigned short* h       = (unsigned short*)alloc((size_t)T_TOK * NTOPK * INTERS * 2);
    unsigned short* hs      = (unsigned short*)alloc((size_t)T_TOK * SINTER * 2);

    const size_t nW = (size_t)NEXP * INTERS * DIMSZ;
    const size_t nS = (size_t)SINTER * DIMSZ;
    const size_t yBytes = (size_t)T_TOK * NTOPK * DIMSZ * 4;
    const size_t needed = 3 * (nW * 2) + 3 * (nS * 2) + yBytes + 8 * 256;
    const bool FAST = (off + needed) <= ws_size;

    hipMemsetAsync(counts, 0, NEXP * 4, stream);

    const int n4x = T_TOK * DIMSZ / 4;

    if (FAST) {
        unsigned short* w11b = (unsigned short*)alloc(nW * 2);
        unsigned short* w33b = (unsigned short*)alloc(nW * 2);
        unsigned short* w22b = (unsigned short*)alloc(nW * 2);
        unsigned short* sw1b = (unsigned short*)alloc(nS * 2);
        unsigned short* sw3b = (unsigned short*)alloc(nS * 2);
        unsigned short* sw2b = (unsigned short*)alloc(nS * 2);
        float*          yexp = (float*)alloc(yBytes);

        // convert only what fc1 needs up front; w22/sw2 convert inside fc1_all
        CvtJobs5 jobs;
        jobs.src[0] = (const float4*)x;   jobs.dst[0] = xb;   jobs.n8[0] = (int)((size_t)T_TOK * DIMSZ / 8);
        jobs.src[1] = (const float4*)w11; jobs.dst[1] = w11b; jobs.n8[1] = (int)(nW / 8);
        jobs.src[2] = (const float4*)w33; jobs.dst[2] = w33b; jobs.n8[2] = (int)(nW / 8);
        jobs.src[3] = (const float4*)sw1; jobs.dst[3] = sw1b; jobs.n8[3] = (int)(nS / 8);
        jobs.src[4] = (const float4*)sw3; jobs.dst[4] = sw3b; jobs.n8[4] = (int)(nS / 8);
        cvt_multi5<<<4096, 256, 0, stream>>>(jobs);

        gate_scores_kernel<<<T_TOK / SCT, 256, 0, stream>>>(x, gw, scores);
        topk_kernel<<<(T_TOK + 255) / 256, 256, 0, stream>>>(scores, counts, toklist, wgts);

        // 256 shared + 1536 (1024 routed + 512 cvt workers, interleaved 2:1)
        fc1_all<<<256 + 1536, 256, 0, stream>>>(
            xb, w11b, w33b, sw1b, sw3b, h, hs, counts, toklist,
            w22, sw2, w22b, sw2b);
        fc2_all<<<256 + 128 * 16, 256, 0, stream>>>(
            h, hs, w22b, sw2b, yexp, out, counts, toklist, wgts);
        combine_kernel<<<2048, 256, 0, stream>>>((const float4*)yexp, (float4*)out, n4x);
    } else {
        cvt_f2b<<<4096, 256, 0, stream>>>((const float4*)x, (ushort4*)xb, n4x);
        gate_scores_kernel<<<T_TOK / SCT, 256, 0, stream>>>(x, gw, scores);
        topk_kernel<<<(T_TOK + 255) / 256, 256, 0, stream>>>(scores, counts, toklist, wgts);

        fc1_fb<false><<<dim3(SINTER / 128, T_TOK / 128, 1), 256, 0, stream>>>(
            xb, sw1, sw3, hs, SINTER, DIMSZ, T_TOK, nullptr, nullptr);
        gemm_fb<SHARED_F32><<<dim3(DIMSZ / 128, T_TOK / 128, 1), 256, 0, stream>>>(
            hs, sw2, out, DIMSZ, SINTER, T_TOK, nullptr, nullptr, nullptr);
        fc1_fb<true><<<dim3(INTERS / 128, T_TOK / 128, NEXP), 256, 0, stream>>>(
            xb, w11, w33, h, INTERS, DIMSZ, 0, counts, toklist);
        gemm_fb<GROUP_FC2><<<dim3(DIMSZ / 128, T_TOK / 128, NEXP), 256, 0, stream>>>(
            h, w22, out, DIMSZ, INTERS, 0, counts, toklist, wgts);
    }
}

// Round 7
// 1093.322 us; speedup vs baseline: 1.2350x; 1.0656x over previous
//
#include <hip/hip_runtime.h>
#include <hip/hip_bf16.h>

#define T_TOK  2048
#define DIMSZ  2048
#define NEXP   32
#define INTERS 1024
#define SINTER 2048
#define NTOPK  6

typedef __bf16 bf16x8 __attribute__((ext_vector_type(8)));
typedef float  f32x4  __attribute__((ext_vector_type(4)));
typedef unsigned short u16x8 __attribute__((ext_vector_type(8)));

__device__ __forceinline__ unsigned short f2b(float f) {
    __hip_bfloat16 h = __float2bfloat16(f);
    return __builtin_bit_cast(unsigned short, h);
}

// async global->LDS, 16B per lane. LDS dest is wave-uniform base + lane*16.
__device__ __forceinline__ void gl_lds16(const unsigned short* g, unsigned short* l) {
    __builtin_amdgcn_global_load_lds(
        (const __attribute__((address_space(1))) void*)g,
        (__attribute__((address_space(3))) void*)l, 16, 0, 0);
}

// ---- B-operand staging: 128 rows x 64 f32 -> bf16 LDS, XOR-swizzled ----
// thread (tid>>3 = row%32, tid&7 = 16B slot); 4 passes cover 128 rows.
// Write slot = s ^ (row&7); read side uses soff = (slot_r ^ (lm&7)) -- the
// same involution (row&7 == lm&7 on the read fragment's row). Inner loop
// and LDS layout identical to the proven gl_lds version.
__device__ __forceinline__ void stage_b_f32(
    const float* __restrict__ B, int n0, int K, int k0,
    unsigned short* __restrict__ Bs, int tid)
{
    const int srow  = tid >> 3;          // 0..31
    const int s     = tid & 7;           // bf16 16B-slot within row
    const int wslot = s ^ (srow & 7);    // row&7 == srow&7 (p*32 ≡ 0 mod 8)
    #pragma unroll
    for (int p = 0; p < 4; ++p) {
        const int row = p * 32 + srow;
        const float* g = B + (size_t)(n0 + row) * K + k0 + s * 8;
        float4 a = *(const float4*)g;
        float4 b = *(const float4*)(g + 4);
        u16x8 o;
        o[0] = f2b(a.x); o[1] = f2b(a.y); o[2] = f2b(a.z); o[3] = f2b(a.w);
        o[4] = f2b(b.x); o[5] = f2b(b.y); o[6] = f2b(b.z); o[7] = f2b(b.w);
        *(u16x8*)&Bs[row * 64 + wslot * 8] = o;
    }
}

// ---------------- x -> bf16 (only remaining conversion pass, 16 MB) ----------------
__global__ void cvt_f2b(const float4* __restrict__ src, unsigned short* __restrict__ dst, int n8) {
    int stride = gridDim.x * blockDim.x;
    for (int i = blockIdx.x * blockDim.x + threadIdx.x; i < n8; i += stride) {
        float4 a = src[2 * (size_t)i];
        float4 b = src[2 * (size_t)i + 1];
        u16x8 o;
        o[0] = f2b(a.x); o[1] = f2b(a.y); o[2] = f2b(a.z); o[3] = f2b(a.w);
        o[4] = f2b(b.x); o[5] = f2b(b.y); o[6] = f2b(b.z); o[7] = f2b(b.w);
        *(u16x8*)&dst[(size_t)i * 8] = o;
    }
}

// ---------------- gate scores: scores[T,E] = sigmoid(x @ gw^T), fp32 ----------------
#define SCT 8
#define SCK 128
__global__ __launch_bounds__(256) void gate_scores_kernel(
    const float* __restrict__ x, const float* __restrict__ gw, float* __restrict__ scores)
{
    __shared__ float xs[SCT * SCK];            // 8 x 128
    __shared__ float gs[NEXP * (SCK + 1)];     // 32 x 129 (pad: conflict-free)
    const int t0 = blockIdx.x * SCT;
    const int tid = threadIdx.x;
    const int tl = tid >> 5, e = tid & 31;
    float acc = 0.f;
    for (int k0 = 0; k0 < DIMSZ; k0 += SCK) {
        {
            int row = tid >> 5, d4 = tid & 31;
            *(float4*)&xs[row * SCK + d4 * 4] =
                *(const float4*)&x[(size_t)(t0 + row) * DIMSZ + k0 + d4 * 4];
        }
        #pragma unroll
        for (int i = 0; i < 4; ++i) {
            int lin = tid + i * 256;
            int row = lin >> 5, d4 = lin & 31;
            float4 v = *(const float4*)&gw[(size_t)row * DIMSZ + k0 + d4 * 4];
            float* dst = &gs[row * (SCK + 1) + d4 * 4];
            dst[0] = v.x; dst[1] = v.y; dst[2] = v.z; dst[3] = v.w;
        }
        __syncthreads();
        #pragma unroll 8
        for (int d = 0; d < SCK; ++d)
            acc += xs[tl * SCK + d] * gs[e * (SCK + 1) + d];
        __syncthreads();
    }
    scores[(size_t)(t0 + tl) * NEXP + e] = 1.f / (1.f + expf(-acc));
}

// ---------------- top-k routing (one thread per token) ----------------
__global__ __launch_bounds__(256) void topk_kernel(
    const float* __restrict__ scores,
    int* __restrict__ counts, int* __restrict__ toklist, float* __restrict__ wgts)
{
    int t = blockIdx.x * 256 + threadIdx.x;
    if (t >= T_TOK) return;
    float sc[NEXP];
    #pragma unroll
    for (int e = 0; e < NEXP; ++e) sc[e] = scores[(size_t)t * NEXP + e];

    float gsc[8];
    #pragma unroll
    for (int g = 0; g < 8; ++g) {
        float m = sc[4 * g];
        #pragma unroll
        for (int j = 1; j < 4; ++j) m = fmaxf(m, sc[4 * g + j]);
        gsc[g] = m;
    }
    bool gsel[8] = {false, false, false, false, false, false, false, false};
    for (int it = 0; it < 4; ++it) {
        int bi = -1; float bv = -1e30f;
        #pragma unroll
        for (int g = 0; g < 8; ++g)
            if (!gsel[g] && gsc[g] > bv) { bv = gsc[g]; bi = g; }
        gsel[bi] = true;
    }
    bool esel[NEXP];
    #pragma unroll
    for (int e = 0; e < NEXP; ++e) esel[e] = false;
    int   idx[NTOPK];
    float w[NTOPK];
    float sum = 0.f;
    for (int it = 0; it < NTOPK; ++it) {
        int bi = -1; float bv = -1e30f;
        #pragma unroll
        for (int e = 0; e < NEXP; ++e) {
            if (!gsel[e >> 2] || esel[e]) continue;
            if (sc[e] > bv) { bv = sc[e]; bi = e; }
        }
        esel[bi] = true; idx[it] = bi; w[it] = bv; sum += bv;
    }
    float scale = 2.5f / sum;
    for (int k = 0; k < NTOPK; ++k) {
        int e = idx[k];
        int s = atomicAdd(&counts[e], 1);
        toklist[e * T_TOK + s] = (t << 3) | k;
        wgts[e * T_TOK + s]   = w[k] * scale;
    }
}

// =======================================================================
// fc1_all: 1-D grid 256+1024, shared tiles first (1/CU, overlap with
// routed). B1/B2 read RAW f32 weights via reg-stage+cvt+swizzled
// ds_write (no pre-conversion pass). A = xb bf16 via gl_lds.
// H = silu(A@B1^T) * (A@B2^T), bf16 out.
// =======================================================================
__global__ __launch_bounds__(256, 2) void fc1_all(
    const unsigned short* __restrict__ A,
    const float* __restrict__ w11, const float* __restrict__ w33,
    const float* __restrict__ sw1, const float* __restrict__ sw3,
    unsigned short* __restrict__ h, unsigned short* __restrict__ hs,
    const int* __restrict__ counts, const int* __restrict__ toklist)
{
    constexpr int BM = 128, BN = 128, BK = 64, LDK = 64, K = DIMSZ;
    __shared__ unsigned short As[BM * LDK];
    __shared__ unsigned short B1s[BN * LDK];
    __shared__ unsigned short B2s[BN * LDK];
    __shared__ int aRowS[BM];
    __shared__ int cRowS[BM];
    __shared__ int map[4];   // {isShared, e, ytile, xtile}

    const int tid = threadIdx.x;
    if (tid == 0) {
        const int wgid = blockIdx.x;
        if (wgid < 256) {
            map[0] = 1; map[1] = NEXP; map[2] = wgid >> 4; map[3] = wgid & 15;
        } else {
            const int rid = wgid - 256;          // routed tile id
            const int xt = rid & 7, ty = rid >> 3;
            int acc2 = 0, fe = -1, fy = 0;
            #pragma unroll
            for (int e2 = 0; e2 < NEXP; ++e2) {
                const int nt = (counts[e2] + 127) >> 7;
                if (fe < 0 && ty < acc2 + nt) { fe = e2; fy = ty - acc2; }
                acc2 += nt;
            }
            map[0] = 0; map[1] = fe; map[2] = fy; map[3] = xt;
        }
    }
    __syncthreads();
    const bool SH = (map[0] != 0);
    const int e  = map[1];
    if (!SH && e < 0) return;            // beyond total routed tiles (uniform)
    const int m0 = map[2] * BM;
    const int n0 = map[3] * BN;
    const int N  = SH ? SINTER : INTERS;
    const int M  = SH ? T_TOK : counts[e];

    const size_t eoff = SH ? 0 : (size_t)e * INTERS * DIMSZ;
    const float* B1 = (SH ? sw1 : w11) + eoff;
    const float* B2 = (SH ? sw3 : w33) + eoff;
    unsigned short* Hout = SH ? hs : h;

    if (tid < BM) {
        int r = m0 + tid;
        if (SH) { aRowS[tid] = r; cRowS[tid] = r; }
        else if (r < M) {
            int ent = toklist[e * T_TOK + r];
            int t = ent >> 3, k = ent & 7;
            aRowS[tid] = t; cRowS[tid] = t * NTOPK + k;
        } else { aRowS[tid] = 0; cRowS[tid] = -1; }
    }
    __syncthreads();

    f32x4 acc1[4][4] = {};
    f32x4 acc2v[4][4] = {};

    const int wave = tid >> 6;
    const int lane = tid & 63;
    const int wm = (wave >> 1) * 64;
    const int wn = (wave & 1) * 64;
    const int lm = lane & 15;
    const int quad = lane >> 4;

    // A: per-lane pre-swizzled gl_lds pointers (4 chunks of 8 rows each)
    const unsigned short* aP[4];
    {
        const int l8 = lane >> 3;             // row within chunk (0..7)
        const int sg = (lane & 7) ^ l8;       // pre-swizzled 16B slot within row
        #pragma unroll
        for (int i = 0; i < 4; ++i) {
            const int c = wave * 4 + i;       // chunk 0..15, rows 8c..8c+7
            const int r = c * 8 + l8;
            aP[i] = A + (size_t)aRowS[r] * K + sg * 8;
        }
    }

    for (int k0 = 0; k0 < K; k0 += BK) {
        #pragma unroll
        for (int i = 0; i < 4; ++i) {
            const int c = wave * 4 + i;
            gl_lds16(aP[i] + k0, &As[c * 512]);
        }
        stage_b_f32(B1, n0, K, k0, B1s, tid);
        stage_b_f32(B2, n0, K, k0, B2s, tid);
        __syncthreads();   // drains vmcnt + lgkm -> all staged data visible
        #pragma unroll
        for (int kh = 0; kh < 2; ++kh) {
            const int soff = (((kh << 2) | quad) ^ (lm & 7)) << 3;
            bf16x8 af[4], bf1[4], bf2[4];
            #pragma unroll
            for (int ti = 0; ti < 4; ++ti)
                af[ti] = *(const bf16x8*)&As[(wm + ti * 16 + lm) * LDK + soff];
            #pragma unroll
            for (int tj = 0; tj < 4; ++tj) {
                bf1[tj] = *(const bf16x8*)&B1s[(wn + tj * 16 + lm) * LDK + soff];
                bf2[tj] = *(const bf16x8*)&B2s[(wn + tj * 16 + lm) * LDK + soff];
            }
            #pragma unroll
            for (int ti = 0; ti < 4; ++ti)
                #pragma unroll
                for (int tj = 0; tj < 4; ++tj) {
                    acc1[ti][tj] = __builtin_amdgcn_mfma_f32_16x16x32_bf16(
                        af[ti], bf1[tj], acc1[ti][tj], 0, 0, 0);
                    acc2v[ti][tj] = __builtin_amdgcn_mfma_f32_16x16x32_bf16(
                        af[ti], bf2[tj], acc2v[ti][tj], 0, 0, 0);
                }
        }
        __syncthreads();
    }

    #pragma unroll
    for (int ti = 0; ti < 4; ++ti) {
        #pragma unroll
        for (int r = 0; r < 4; ++r) {
            int lrow = wm + ti * 16 + quad * 4 + r;
            int cr = cRowS[lrow];
            if (cr < 0) continue;
            #pragma unroll
            for (int tj = 0; tj < 4; ++tj) {
                int nn = n0 + wn + tj * 16 + lm;
                float g = acc1[ti][tj][r];
                float u = acc2v[ti][tj][r];
                float hv = g / (1.f + expf(-g)) * u;
                Hout[(size_t)cr * N + nn] = f2b(hv);
            }
        }
    }
}

// =======================================================================
// fc2_all: B = raw f32 (w22/sw2) reg-staged; A = h/hs bf16 via gl_lds.
// MODE 0: merged dense (shared->out store, routed->yexp slot store).
// MODE 1: shared only (grid 256).  MODE 2: routed only, atomic into out.
// =======================================================================
template <int MODE>
__global__ __launch_bounds__(256, 2) void fc2_all(
    const unsigned short* __restrict__ h, const unsigned short* __restrict__ hs,
    const float* __restrict__ w22, const float* __restrict__ sw2,
    float* __restrict__ yexp, float* __restrict__ out,
    const int* __restrict__ counts, const int* __restrict__ toklist,
    const float* __restrict__ wgts)
{
    constexpr int BM = 128, BN = 128, BK = 64, LDK = 64;
    __shared__ unsigned short As[BM * LDK];
    __shared__ unsigned short Bs[BN * LDK];
    __shared__ int   aRowS[BM];
    __shared__ int   cRowS[BM];
    __shared__ float cWS[BM];
    __shared__ int   map[4];

    const int tid = threadIdx.x;
    if (tid == 0) {
        const int wgid = blockIdx.x;
        if (MODE == 1 || (MODE == 0 && wgid < 256)) {
            const int sid = (MODE == 1) ? wgid : wgid;
            map[0] = 1; map[1] = NEXP; map[2] = sid >> 4; map[3] = sid & 15;
        } else {
            const int rid = (MODE == 0) ? (wgid - 256) : wgid;
            const int xt = rid & 15, ty = rid >> 4;
            int acc2 = 0, fe = -1, fy = 0;
            #pragma unroll
            for (int e2 = 0; e2 < NEXP; ++e2) {
                const int nt = (counts[e2] + 127) >> 7;
                if (fe < 0 && ty < acc2 + nt) { fe = e2; fy = ty - acc2; }
                acc2 += nt;
            }
            map[0] = 0; map[1] = fe; map[2] = fy; map[3] = xt;
        }
    }
    __syncthreads();
    const bool SH = (map[0] != 0);
    const int e  = map[1];
    if (!SH && e < 0) return;
    const int m0 = map[2] * BM;
    const int n0 = map[3] * BN;
    const int K  = SH ? SINTER : INTERS;
    const int M  = SH ? T_TOK : counts[e];

    const unsigned short* Asrc = SH ? hs : h;   // row stride == K for both
    const float* B = SH ? sw2 : (w22 + (size_t)e * DIMSZ * INTERS);
    float* C = SH ? out : ((MODE == 2) ? out : yexp);

    if (tid < BM) {
        int r = m0 + tid;
        if (SH) { aRowS[tid] = r; cRowS[tid] = r; cWS[tid] = 1.f; }
        else if (r < M) {
            int ent = toklist[e * T_TOK + r];
            int slot = (ent >> 3) * NTOPK + (ent & 7);
            aRowS[tid] = slot;
            cRowS[tid] = (MODE == 2) ? (ent >> 3) : slot;
            cWS[tid] = wgts[e * T_TOK + r];
        } else { aRowS[tid] = 0; cRowS[tid] = -1; cWS[tid] = 0.f; }
    }
    __syncthreads();

    f32x4 acc[4][4] = {};

    const int wave = tid >> 6;
    const int lane = tid & 63;
    const int wm = (wave >> 1) * 64;
    const int wn = (wave & 1) * 64;
    const int lm = lane & 15;
    const int quad = lane >> 4;

    const unsigned short* aP[4];
    {
        const int l8 = lane >> 3;
        const int sg = (lane & 7) ^ l8;
        #pragma unroll
        for (int i = 0; i < 4; ++i) {
            const int c = wave * 4 + i;
            const int r = c * 8 + l8;
            aP[i] = Asrc + (size_t)aRowS[r] * K + sg * 8;
        }
    }

    for (int k0 = 0; k0 < K; k0 += BK) {
        #pragma unroll
        for (int i = 0; i < 4; ++i) {
            const int c = wave * 4 + i;
            gl_lds16(aP[i] + k0, &As[c * 512]);
        }
        stage_b_f32(B, n0, K, k0, Bs, tid);
        __syncthreads();
        #pragma unroll
        for (int kh = 0; kh < 2; ++kh) {
            const int soff = (((kh << 2) | quad) ^ (lm & 7)) << 3;
            bf16x8 af[4], bfr[4];
            #pragma unroll
            for (int ti = 0; ti < 4; ++ti)
                af[ti] = *(const bf16x8*)&As[(wm + ti * 16 + lm) * LDK + soff];
            #pragma unroll
            for (int tj = 0; tj < 4; ++tj)
                bfr[tj] = *(const bf16x8*)&Bs[(wn + tj * 16 + lm) * LDK + soff];
            #pragma unroll
            for (int ti = 0; ti < 4; ++ti)
                #pragma unroll
                for (int tj = 0; tj < 4; ++tj)
                    acc[ti][tj] = __builtin_amdgcn_mfma_f32_16x16x32_bf16(
                        af[ti], bfr[tj], acc[ti][tj], 0, 0, 0);
        }
        __syncthreads();
    }

    #pragma unroll
    for (int ti = 0; ti < 4; ++ti) {
        #pragma unroll
        for (int r = 0; r < 4; ++r) {
            int lrow = wm + ti * 16 + quad * 4 + r;
            int cr = cRowS[lrow];
            if (cr < 0) continue;
            #pragma unroll
            for (int tj = 0; tj < 4; ++tj) {
                int nn = n0 + wn + tj * 16 + lm;
                float v = acc[ti][tj][r] * cWS[lrow];
                if (MODE == 2 && !SH)
                    atomicAdd(&C[(size_t)cr * DIMSZ + nn], v);
                else
                    C[(size_t)cr * DIMSZ + nn] = v;
            }
        }
    }
}

// ---------------- combine: out[t,:] += sum_k yexp[t*6+k,:] ----------------
__global__ __launch_bounds__(256) void combine_kernel(
    const float4* __restrict__ yexp, float4* __restrict__ out, int n4)
{
    const int D4 = DIMSZ / 4;   // 512
    int stride = gridDim.x * blockDim.x;
    for (int i = blockIdx.x * blockDim.x + threadIdx.x; i < n4; i += stride) {
        int t = i / D4, d4 = i - t * D4;
        const float4* r = yexp + (size_t)t * NTOPK * D4 + d4;
        float4 a = out[i];
        #pragma unroll
        for (int k = 0; k < NTOPK; ++k) {
            float4 s = r[(size_t)k * D4];
            a.x += s.x; a.y += s.y; a.z += s.z; a.w += s.w;
        }
        out[i] = a;
    }
}

extern "C" void kernel_launch(void* const* d_in, const int* in_sizes, int n_in,
                              void* d_out, int out_size, void* d_ws, size_t ws_size,
                              hipStream_t stream)
{
    const float* x   = (const float*)d_in[0];
    const float* gw  = (const float*)d_in[1];
    const float* w11 = (const float*)d_in[2];
    const float* w33 = (const float*)d_in[3];
    const float* w22 = (const float*)d_in[4];
    const float* sw1 = (const float*)d_in[5];
    const float* sw2 = (const float*)d_in[6];
    const float* sw3 = (const float*)d_in[7];
    float* out = (float*)d_out;

    char* ws = (char*)d_ws;
    size_t off = 0;
    auto alloc = [&](size_t b) { void* p = ws + off; off = (off + b + 255) & ~(size_t)255; return p; };
    int*            counts  = (int*)alloc(NEXP * 4);
    int*            toklist = (int*)alloc((size_t)NEXP * T_TOK * 4);
    float*          wgts    = (float*)alloc((size_t)NEXP * T_TOK * 4);
    float*          scores  = (float*)alloc((size_t)T_TOK * NEXP * 4);
    unsigned short* xb      = (unsigned short*)alloc((size_t)T_TOK * DIMSZ * 2);
    unsigned short* h       = (unsigned short*)alloc((size_t)T_TOK * NTOPK * INTERS * 2);
    unsigned short* hs      = (unsigned short*)alloc((size_t)T_TOK * SINTER * 2);

    const size_t yBytes = (size_t)T_TOK * NTOPK * DIMSZ * 4;   // 100.7 MB
    const bool DENSE = (off + yBytes + 256) <= ws_size;
    float* yexp = DENSE ? (float*)alloc(yBytes) : nullptr;

    hipMemsetAsync(counts, 0, NEXP * 4, stream);

    const int n4x = T_TOK * DIMSZ / 4;
    cvt_f2b<<<1024, 256, 0, stream>>>((const float4*)x, xb, T_TOK * DIMSZ / 8);

    gate_scores_kernel<<<T_TOK / SCT, 256, 0, stream>>>(x, gw, scores);
    topk_kernel<<<(T_TOK + 255) / 256, 256, 0, stream>>>(scores, counts, toklist, wgts);

    // shared tiles first (256 = 1/CU), routed tiles fill remaining slots
    fc1_all<<<256 + 1024, 256, 0, stream>>>(
        xb, w11, w33, sw1, sw3, h, hs, counts, toklist);

    if (DENSE) {
        fc2_all<0><<<256 + 2048, 256, 0, stream>>>(
            h, hs, w22, sw2, yexp, out, counts, toklist, wgts);
        combine_kernel<<<2048, 256, 0, stream>>>((const float4*)yexp, (float4*)out, n4x);
    } else {
        // fallback: shared overwrites out first, then routed atomically adds
        fc2_all<1><<<256, 256, 0, stream>>>(
            h, hs, w22, sw2, nullptr, out, counts, toklist, wgts);
        fc2_all<2><<<2048, 256, 0, stream>>>(
            h, hs, w22, sw2, nullptr, out, counts, toklist, wgts);
    }
}